// Round 3
// baseline (2540.534 us; speedup 1.0000x reference)
//
#include <hip/hip_runtime.h>
#include <hip/hip_bf16.h>

#define N_NODES 50000
#define E_EDGES 300000
#define NGRAPH 64
#define KTOT 16512   // 1024*16 kf + 128 pad chunk (first 16 carry b2)
#define KC 128
#define NCHUNK 129
#define LNEPS 1e-5f
#define NBLK_N 196   // ceil(50000/256)
#define NBLK_P 12500 // N_NODES/4
// prescale so perm-truncate to bf16 ~= round-to-nearest (adds 0.375..0.75 ulp before trunc)
#define RPRE 1.00146484375f

typedef __bf16 bf16x8 __attribute__((ext_vector_type(8)));
typedef float floatx4 __attribute__((ext_vector_type(4)));
typedef float f32x2 __attribute__((ext_vector_type(2)));
typedef unsigned int u32x4 __attribute__((ext_vector_type(4)));

__device__ __forceinline__ void async_load16(const void* g, void* l) {
  __builtin_amdgcn_global_load_lds(
      (__attribute__((address_space(1))) void*)g,
      (__attribute__((address_space(3))) void*)l, 16, 0, 0);
}

// pack two f32 (pre-scaled) -> bf16x2 by truncation: 1 v_perm
__device__ __forceinline__ unsigned pkt(f32x2 p) {
  return __builtin_amdgcn_perm(__float_as_uint(p[1]), __float_as_uint(p[0]), 0x07060302u);
}

// ---------------- prep: Tt[h][kf] bf16 via LDS tile transpose ----------------
__global__ void k_prep(const float* __restrict__ w2, const float* __restrict__ b2,
                       __bf16* __restrict__ Tt) {
  __shared__ float tile[64][65];
  int t = threadIdx.x;
  int kf0 = blockIdx.x * 64;      // 258 blocks
  int r4 = t >> 6;
  int cc = t & 63;
#pragma unroll
  for (int p = 0; p < 16; ++p) {
    int row = p * 4 + r4;
    int kf = kf0 + row;
    float v = 0.f;
    if (kf < 16384) {
      int k = kf >> 4, f = kf & 15;
      v = w2[k * 1024 + f * 64 + cc];      // coalesced
    } else if (kf < 16400) {
      v = b2[(kf - 16384) * 64 + cc];
    }
    tile[row][cc] = v;
  }
  __syncthreads();
#pragma unroll
  for (int p = 0; p < 16; ++p) {
    int h = p * 4 + r4;
    Tt[(size_t)h * KTOT + kf0 + cc] = (__bf16)tile[cc][h];
  }
}

__global__ void k_prepw(const float* __restrict__ w1, float* __restrict__ W1t) {
  int i = blockIdx.x * 256 + threadIdx.x;
  if (i < 8192) { int k = i >> 3, j = i & 7; W1t[i] = w1[j * 1024 + k]; }
}

// ---------------- CSR build ----------------
__global__ void k_cnt(const int* __restrict__ ei, int* __restrict__ degI) {
  int e = blockIdx.x * 256 + threadIdx.x;
  if (e < E_EDGES) atomicAdd(&degI[ei[E_EDGES + e]], 1);
}

__global__ void k_scanA(const int* __restrict__ degI, int* __restrict__ bsum) {
  __shared__ int sm[256];
  int t = threadIdx.x;
  int i = blockIdx.x * 256 + t;
  sm[t] = (i < N_NODES) ? degI[i] : 0;
  __syncthreads();
  for (int off = 128; off > 0; off >>= 1) {
    if (t < off) sm[t] += sm[t + off];
    __syncthreads();
  }
  if (t == 0) bsum[blockIdx.x] = sm[0];
}

__global__ void k_scanB(const int* __restrict__ bsum, int* __restrict__ bpre) {
  __shared__ int s[256];
  int t = threadIdx.x;
  int v = (t < NBLK_N) ? bsum[t] : 0;
  s[t] = v;
  __syncthreads();
  for (int off = 1; off < 256; off <<= 1) {
    int add = (t >= off) ? s[t - off] : 0;
    __syncthreads();
    s[t] += add;
    __syncthreads();
  }
  if (t < NBLK_N) bpre[t] = s[t] - v;
}

__global__ void k_scanC(const int* __restrict__ degI, const int* __restrict__ bpre,
                        int* __restrict__ rowptr, int* __restrict__ cursor) {
  __shared__ int s[256];
  int t = threadIdx.x;
  int i = blockIdx.x * 256 + t;
  int d = (i < N_NODES) ? degI[i] : 0;
  s[t] = d;
  __syncthreads();
  for (int off = 1; off < 256; off <<= 1) {
    int add = (t >= off) ? s[t - off] : 0;
    __syncthreads();
    s[t] += add;
    __syncthreads();
  }
  int r = bpre[blockIdx.x] + s[t] - d;   // exclusive
  if (i < N_NODES) {
    rowptr[i] = r;
    cursor[i] = r;
    if (i == N_NODES - 1) rowptr[N_NODES] = r + d;
  }
}

__global__ void k_scatter(const int* __restrict__ ei, int* __restrict__ cursor,
                          int* __restrict__ colsrc) {
  int e = blockIdx.x * 256 + threadIdx.x;
  if (e < E_EDGES) {
    int s = ei[e], d = ei[E_EDGES + e];
    int pos = atomicAdd(&cursor[d], 1);
    colsrc[pos] = s;
  }
}

// ---------------- NNConv fused MFMA GEMM ----------------
__global__ __launch_bounds__(256, 4)
void k_nnconv(const float* __restrict__ x, const int* __restrict__ ei,
              const float* __restrict__ ea, const float* __restrict__ W1t,
              const float* __restrict__ b1, const __bf16* __restrict__ Tt,
              float* __restrict__ agg) {
  __shared__ __align__(16) __bf16 sB[2][64 * KC];  // 32 KB
  __shared__ int sSrc[256];
  __shared__ int sDst[256];

  const int tid = threadIdx.x;
  const int wv = tid >> 6;
  const int lane = tid & 63;
  const int l15 = lane & 15;
  const int quad = lane >> 4;
  const int qxl = quad ^ l15;
  const int base = blockIdx.x * 256;

  int e = base + tid;
  bool valid = e < E_EDGES;
  sSrc[tid] = valid ? ei[e] : 0;
  sDst[tid] = valid ? ei[E_EDGES + e] : -1;

  float eaw[8];
  {
    const float4* p = (const float4*)(ea + (size_t)(valid ? e : 0) * 8);
    float4 a0 = p[0], a1 = p[1];
    eaw[0] = a0.x; eaw[1] = a0.y; eaw[2] = a0.z; eaw[3] = a0.w;
    eaw[4] = a1.x; eaw[5] = a1.y; eaw[6] = a1.z; eaw[7] = a1.w;
  }
  __syncthreads();

  // persistent pre-scaled x fragments (f32x2 pairs)
  const int f0 = (quad & 1) * 8;
  f32x2 xf2[4][4];
#pragma unroll
  for (int mb = 0; mb < 4; ++mb) {
    int el = wv * 64 + mb * 16 + l15;
    const float4* px = (const float4*)(x + (size_t)sSrc[el] * 16 + f0);
    float4 v0 = px[0], v1 = px[1];
    xf2[mb][0] = (f32x2){v0.x * RPRE, v0.y * RPRE};
    xf2[mb][1] = (f32x2){v0.z * RPRE, v0.w * RPRE};
    xf2[mb][2] = (f32x2){v1.x * RPRE, v1.y * RPRE};
    xf2[mb][3] = (f32x2){v1.z * RPRE, v1.w * RPRE};
  }

  // staging source pointers (advance by KC each chunk)
  const __bf16* gsrc[4];
#pragma unroll
  for (int it = 0; it < 4; ++it) {
    int q = it * 256 + tid;
    int h = q >> 4;
    int cc = (q & 15) ^ (h & 15);
    gsrc[it] = Tt + (size_t)h * KTOT + cc * 8;
  }

  auto stageB = [&](int buf) {
#pragma unroll
    for (int it = 0; it < 4; ++it) {
      async_load16(gsrc[it], &sB[buf][(it * 256 + tid) * 8]);
      gsrc[it] += KC;
    }
  };

  float rr[8];
  auto calcR = [&](int c, const float* w1p, const float* b1p) {
    if (c < 128) {   // uniform branch
#pragma unroll
      for (int kk = 0; kk < 8; ++kk) {
        const float4* w = (const float4*)(w1p + kk * 8);  // uniform addr -> s_load
        float4 w0 = w[0], w1v = w[1];
        float v = b1p[kk];
        v += eaw[0] * w0.x + eaw[1] * w0.y + eaw[2] * w0.z + eaw[3] * w0.w;
        v += eaw[4] * w1v.x + eaw[5] * w1v.y + eaw[6] * w1v.z + eaw[7] * w1v.w;
        rr[kk] = fmaxf(v, 0.f);
      }
    } else {
#pragma unroll
      for (int kk = 0; kk < 8; ++kk)
        rr[kk] = ((c * 8 + kk) == 1024) ? 1.f : 0.f;  // b2 row
    }
  };

  floatx4 acc[4][4];
#pragma unroll
  for (int mb = 0; mb < 4; ++mb)
#pragma unroll
    for (int nb = 0; nb < 4; ++nb) acc[mb][nb] = floatx4{0.f, 0.f, 0.f, 0.f};

  stageB(0);
  calcR(0, W1t, b1);
  const float* w1p = W1t + 64;
  const float* b1p = b1 + 8;
  int buf = 0;
  for (int c = 0; c < NCHUNK; ++c) {
    __syncthreads();
    if (c + 1 < NCHUNK) stageB(buf ^ 1);
#pragma unroll
    for (int ks = 0; ks < 4; ++ks) {
      int t1 = qxl ^ (ks * 4);
      bf16x8 bfr[4];
#pragma unroll
      for (int nb = 0; nb < 4; ++nb)
        bfr[nb] = *(const bf16x8*)&sB[buf][(nb * 16 + l15) * KC + t1 * 8];
      float r0 = rr[2 * ks], r1 = rr[2 * ks + 1];
#pragma unroll
      for (int mb = 0; mb < 4; ++mb) {
        float rv0 = __shfl(r0, mb * 16 + l15);
        float rv1 = __shfl(r1, mb * 16 + l15);
        float rv = (quad & 2) ? rv1 : rv0;
        f32x2 rv2 = {rv, rv};
        u32x4 U;
        U[0] = pkt(rv2 * xf2[mb][0]);
        U[1] = pkt(rv2 * xf2[mb][1]);
        U[2] = pkt(rv2 * xf2[mb][2]);
        U[3] = pkt(rv2 * xf2[mb][3]);
        bf16x8 A = __builtin_bit_cast(bf16x8, U);
#pragma unroll
        for (int nb = 0; nb < 4; ++nb)
          acc[mb][nb] = __builtin_amdgcn_mfma_f32_16x16x32_bf16(A, bfr[nb], acc[mb][nb], 0, 0, 0);
      }
    }
    if (c + 1 < NCHUNK) {
      calcR(c + 1, w1p, b1p);  // wave-synchronous: all shfls of rr above are done
      w1p += 64; b1p += 8;
    }
    buf ^= 1;
  }

  // epilogue: scatter msg to agg[dst]  (C layout: row=quad*4+reg, col=l15)
#pragma unroll
  for (int mb = 0; mb < 4; ++mb) {
    int el = wv * 64 + mb * 16 + quad * 4;
#pragma unroll
    for (int reg = 0; reg < 4; ++reg) {
      int dd = sDst[el + reg];
      if (dd >= 0) {
#pragma unroll
        for (int nb = 0; nb < 4; ++nb)
          atomicAdd(&agg[(size_t)dd * 64 + nb * 16 + l15], acc[mb][nb][reg]);
      }
    }
  }
}

// ---------------- h = relu(x@rootw + agg/deg + b); LN1 partials ----------------
__global__ void k_root(const float* __restrict__ x, const float* __restrict__ rootw,
                       const float* __restrict__ conv1b, const float* __restrict__ agg,
                       const int* __restrict__ degI, float* __restrict__ hpre,
                       float* __restrict__ rpart) {
  __shared__ float sW[1024];
  __shared__ float sx[64];
  __shared__ float red[8];
  int t = threadIdx.x;
  int blk = blockIdx.x;
#pragma unroll
  for (int i = 0; i < 4; ++i) sW[t + i * 256] = rootw[t + i * 256];
  if (t < 64) sx[t] = x[(size_t)blk * 64 + t];
  __syncthreads();
  int ln = t >> 6, h = t & 63;
  int n = blk * 4 + ln;
  float acc = conv1b[h];
#pragma unroll
  for (int f = 0; f < 16; ++f) acc += sx[ln * 16 + f] * sW[f * 64 + h];
  float dv = fmaxf((float)degI[n], 1.0f);
  float v = acc + agg[(size_t)n * 64 + h] / dv;
  v = fmaxf(v, 0.f);
  hpre[(size_t)n * 64 + h] = v;
  float s1 = v, s2 = v * v;
  for (int o = 32; o > 0; o >>= 1) { s1 += __shfl_down(s1, o); s2 += __shfl_down(s2, o); }
  if ((t & 63) == 0) { red[t >> 6] = s1; red[4 + (t >> 6)] = s2; }
  __syncthreads();
  if (t == 0) {
    rpart[blk * 2] = red[0] + red[1] + red[2] + red[3];
    rpart[blk * 2 + 1] = red[4] + red[5] + red[6] + red[7];
  }
}

// reduce LN1 partials; fold LN1 into gat_w
__global__ void k_fold1(const float* __restrict__ rpart, const float* __restrict__ n1w,
                        const float* __restrict__ n1b, const float* __restrict__ gatw,
                        float* __restrict__ gw2, float* __restrict__ tb) {
  __shared__ float red[8];
  __shared__ float sMI[2];
  __shared__ float sS[64], sT[64];
  int t = threadIdx.x;
  int wv = t >> 6, lane = t & 63;
  float a = 0.f, b = 0.f;
  for (int i = t; i < NBLK_P; i += 256) { a += rpart[2 * i]; b += rpart[2 * i + 1]; }
  for (int o = 32; o > 0; o >>= 1) { a += __shfl_down(a, o); b += __shfl_down(b, o); }
  if (lane == 0) { red[wv] = a; red[4 + wv] = b; }
  __syncthreads();
  if (t == 0) {
    float A = red[0] + red[1] + red[2] + red[3];
    float B = red[4] + red[5] + red[6] + red[7];
    const float M = (float)N_NODES * 64.f;
    float mu = A / M;
    float var = fmaxf(B / M - mu * mu, 0.f);
    sMI[0] = mu;
    sMI[1] = 1.f / (sqrtf(var) + LNEPS);
  }
  __syncthreads();
  if (t < 64) {
    float mu = sMI[0], inv = sMI[1];
    sS[t] = inv * n1w[t];
    sT[t] = n1b[t] - mu * inv * n1w[t];
  }
  __syncthreads();
  if (t < 64) {
    float acc = 0.f;
    for (int i = 0; i < 64; ++i) {
      float g = gatw[i * 64 + t];
      gw2[i * 64 + t] = sS[i] * g;
      acc += sT[i] * g;
    }
    tb[t] = acc;
  }
}

// xh = hpre@gw2 + tb ; attention scalars
__global__ void k_gatlin(const float* __restrict__ hpre, const float* __restrict__ gw2,
                         const float* __restrict__ tb, const float* __restrict__ attS,
                         const float* __restrict__ attD, float* __restrict__ xh,
                         float* __restrict__ asrc, float* __restrict__ adst) {
  __shared__ float sW[4096];
  __shared__ float sh[256];
  __shared__ float sxh[256];
  int t = threadIdx.x;
  int blk = blockIdx.x;
#pragma unroll
  for (int i = 0; i < 16; ++i) sW[t + i * 256] = gw2[t + i * 256];
  sh[t] = hpre[(size_t)blk * 256 + t];
  __syncthreads();
  int ln = t >> 6, h = t & 63;
  float acc = tb[h];
  for (int i = 0; i < 64; ++i) acc += sh[ln * 64 + i] * sW[i * 64 + h];
  xh[(size_t)blk * 256 + t] = acc;
  sxh[t] = acc;
  __syncthreads();
  if (t < 32) {
    int ln2 = t >> 3, rem = t & 7;
    int hd = rem & 3;
    const float* av = (rem >> 2) ? attD : attS;
    float a = 0.f;
#pragma unroll
    for (int d = 0; d < 16; ++d) a += sxh[ln2 * 64 + hd * 16 + d] * av[hd * 16 + d];
    int n = blk * 4 + ln2;
    if (rem >> 2) adst[n * 4 + hd] = a; else asrc[n * 4 + hd] = a;
  }
}

// ---------------- GAT: CSR gather, online softmax, fused relu + LN2 partials ----------------
__global__ void k_gat(const int* __restrict__ rowptr, const int* __restrict__ colsrc,
                      const float* __restrict__ xh, const float* __restrict__ asrc,
                      const float* __restrict__ adst, const float* __restrict__ gatb,
                      float* __restrict__ act, float* __restrict__ gpart) {
  __shared__ float sP[4][256];
  __shared__ int sS[4][64];
  __shared__ float sRed[8];
  int t = threadIdx.x;
  int wv = t >> 6, lane = t & 63;
  int n = blockIdx.x * 4 + wv;
  int start = rowptr[n], end = rowptr[n + 1];
  int deg = end - start;
  int myhd = lane >> 4;
  float ad[4];
#pragma unroll
  for (int hd = 0; hd < 4; ++hd) ad[hd] = adst[n * 4 + hd];
  float m[4] = {-1e30f, -1e30f, -1e30f, -1e30f};
  float l[4] = {0.f, 0.f, 0.f, 0.f};
  float O = 0.f;
  int items = deg + 1;  // + self loop
  for (int t0 = 0; t0 < items; t0 += 64) {
    int cnt = min(64, items - t0);
    int idx = t0 + lane;
    bool has = lane < cnt;
    int s = n;
    if (has && idx < deg) s = colsrc[start + idx];
    float a[4];
#pragma unroll
    for (int hd = 0; hd < 4; ++hd) {
      float av = has ? (asrc[s * 4 + hd] + ad[hd]) : -1e30f;
      a[hd] = (av > 0.f) ? av : 0.2f * av;  // leaky relu 0.2
    }
    float tm[4];
#pragma unroll
    for (int hd = 0; hd < 4; ++hd) tm[hd] = a[hd];
#pragma unroll
    for (int off = 32; off > 0; off >>= 1)
#pragma unroll
      for (int hd = 0; hd < 4; ++hd) tm[hd] = fmaxf(tm[hd], __shfl_xor(tm[hd], off));
    float p[4];
#pragma unroll
    for (int hd = 0; hd < 4; ++hd) {
      float mn = fmaxf(m[hd], tm[hd]);
      float sc = __expf(m[hd] - mn);
      l[hd] *= sc;
      if (hd == myhd) O *= sc;
      m[hd] = mn;
      p[hd] = has ? __expf(a[hd] - mn) : 0.f;
    }
    float ts[4];
#pragma unroll
    for (int hd = 0; hd < 4; ++hd) ts[hd] = p[hd];
#pragma unroll
    for (int off = 32; off > 0; off >>= 1)
#pragma unroll
      for (int hd = 0; hd < 4; ++hd) ts[hd] += __shfl_xor(ts[hd], off);
#pragma unroll
    for (int hd = 0; hd < 4; ++hd) l[hd] += ts[hd];
    sS[wv][lane] = s;
#pragma unroll
    for (int hd = 0; hd < 4; ++hd) sP[wv][lane * 4 + hd] = p[hd];
    // wave-private LDS region: program order suffices, no barrier
    for (int e2 = 0; e2 < cnt; ++e2) {
      int ss = sS[wv][e2];
      float pp = sP[wv][e2 * 4 + myhd];
      O = fmaf(pp, xh[(size_t)ss * 64 + lane], O);
    }
  }
  float lmy = (myhd & 2) ? ((myhd & 1) ? l[3] : l[2]) : ((myhd & 1) ? l[1] : l[0]);
  float outv = O / (lmy + 1e-16f);
  float v = fmaxf(outv + gatb[lane], 0.f);
  act[(size_t)n * 64 + lane] = v;
  float s1 = v, s2 = v * v;
#pragma unroll
  for (int off = 32; off > 0; off >>= 1) { s1 += __shfl_down(s1, off); s2 += __shfl_down(s2, off); }
  if (lane == 0) { sRed[wv] = s1; sRed[4 + wv] = s2; }
  __syncthreads();
  if (t == 0) {
    gpart[blockIdx.x * 2] = sRed[0] + sRed[1] + sRed[2] + sRed[3];
    gpart[blockIdx.x * 2 + 1] = sRed[4] + sRed[5] + sRed[6] + sRed[7];
  }
}

// reduce LN2 partials; fold LN2 + linear head into wl
__global__ void k_fold2(const float* __restrict__ gpart, const float* __restrict__ n2w,
                        const float* __restrict__ n2b, const float* __restrict__ linw,
                        const float* __restrict__ linb, float* __restrict__ wl) {
  __shared__ float red[8];
  __shared__ float sMI[2];
  int t = threadIdx.x;
  int wv = t >> 6, lane = t & 63;
  float a = 0.f, b = 0.f;
  for (int i = t; i < NBLK_P; i += 256) { a += gpart[2 * i]; b += gpart[2 * i + 1]; }
  for (int o = 32; o > 0; o >>= 1) { a += __shfl_down(a, o); b += __shfl_down(b, o); }
  if (lane == 0) { red[wv] = a; red[4 + wv] = b; }
  __syncthreads();
  if (t == 0) {
    float A = red[0] + red[1] + red[2] + red[3];
    float B = red[4] + red[5] + red[6] + red[7];
    const float M = (float)N_NODES * 64.f;
    float mu = A / M;
    float var = fmaxf(B / M - mu * mu, 0.f);
    sMI[0] = mu;
    sMI[1] = 1.f / (sqrtf(var) + LNEPS);
  }
  __syncthreads();
  if (t < 64) {
    float mu = sMI[0], inv = sMI[1];
    float w = inv * n2w[t] * linw[t];
    float p = (n2b[t] - mu * inv * n2w[t]) * linw[t];
    wl[t] = w;
    for (int o = 32; o > 0; o >>= 1) p += __shfl_down(p, o);
    if (t == 0) wl[64] = p + linb[0];
  }
}

// per-graph segmented pool + head (batch is sorted; zero atomics)
__global__ void k_out(const float* __restrict__ act, const float* __restrict__ wl,
                      const int* __restrict__ batch, float* __restrict__ out) {
  __shared__ float red[4];
  __shared__ float swl[64];
  int g = blockIdx.x;
  int t = threadIdx.x;
  int wv = t >> 6, lane = t & 63;
  if (t < 64) swl[t] = wl[t];
  __syncthreads();
  auto lbound = [&](int key) {
    int lo = 0, hi = N_NODES;
    while (lo < hi) { int mid = (lo + hi) >> 1; if (batch[mid] < key) lo = mid + 1; else hi = mid; }
    return lo;
  };
  int lo = lbound(g), hi = lbound(g + 1);
  int cntn = hi - lo;
  float s = 0.f;
  for (int idx = t; idx < cntn * 64; idx += 256) {
    int n = lo + (idx >> 6);
    int d = idx & 63;
    s += act[(size_t)n * 64 + d] * swl[d];
  }
  for (int o = 32; o > 0; o >>= 1) s += __shfl_down(s, o);
  if (lane == 0) red[wv] = s;
  __syncthreads();
  if (t == 0)
    out[g] = (red[0] + red[1] + red[2] + red[3]) / fmaxf((float)cntn, 1.f) + wl[64];
}

// ---------------- workspace layout (bytes, 64B aligned) ----------------
#define OFF_AGG     0UL
#define OFF_DEGI    12800000UL
#define ZBYTES      13000000UL
#define OFF_RPART   13000000UL
#define OFF_GPART   13100032UL
#define OFF_ROWPTR  13200064UL
#define OFF_CURSOR  13400128UL
#define OFF_BSUM    13600192UL
#define OFF_BPRE    13601024UL
#define OFF_COLSRC  13601856UL
#define OFF_TT      14801856UL
#define OFF_W1T     16915392UL
#define OFF_GW2     16948160UL
#define OFF_TB      16964544UL
#define OFF_WL      16964800UL
#define OFF_ASRC    16965120UL
#define OFF_ADST    17765120UL
#define OFF_HPRE    18565120UL
#define OFF_XH      31365120UL
#define OFF_ACT     44165120UL
#define WS_NEED     56965120UL

extern "C" void kernel_launch(void* const* d_in, const int* in_sizes, int n_in,
                              void* d_out, int out_size, void* d_ws, size_t ws_size,
                              hipStream_t stream) {
  const float* x = (const float*)d_in[0];
  const int* ei = (const int*)d_in[1];
  const float* ea = (const float*)d_in[2];
  const int* batch = (const int*)d_in[3];
  const float* w1 = (const float*)d_in[4];
  const float* b1 = (const float*)d_in[5];
  const float* w2 = (const float*)d_in[6];
  const float* b2 = (const float*)d_in[7];
  const float* rootw = (const float*)d_in[8];
  const float* conv1b = (const float*)d_in[9];
  const float* n1w = (const float*)d_in[10];
  const float* n1b = (const float*)d_in[11];
  const float* gatw = (const float*)d_in[12];
  const float* attS = (const float*)d_in[13];
  const float* attD = (const float*)d_in[14];
  const float* gatb = (const float*)d_in[15];
  const float* n2w = (const float*)d_in[16];
  const float* n2b = (const float*)d_in[17];
  const float* linw = (const float*)d_in[18];
  const float* linb = (const float*)d_in[19];

  if (ws_size < WS_NEED) return;
  char* ws = (char*)d_ws;
  float* agg    = (float*)(ws + OFF_AGG);
  int* degI     = (int*)(ws + OFF_DEGI);
  float* rpart  = (float*)(ws + OFF_RPART);
  float* gpart  = (float*)(ws + OFF_GPART);
  int* rowptr   = (int*)(ws + OFF_ROWPTR);
  int* cursor   = (int*)(ws + OFF_CURSOR);
  int* bsum     = (int*)(ws + OFF_BSUM);
  int* bpre     = (int*)(ws + OFF_BPRE);
  int* colsrc   = (int*)(ws + OFF_COLSRC);
  __bf16* Tt    = (__bf16*)(ws + OFF_TT);
  float* W1t    = (float*)(ws + OFF_W1T);
  float* gw2    = (float*)(ws + OFF_GW2);
  float* tb     = (float*)(ws + OFF_TB);
  float* wl     = (float*)(ws + OFF_WL);
  float* asrc   = (float*)(ws + OFF_ASRC);
  float* adst   = (float*)(ws + OFF_ADST);
  float* hpre   = (float*)(ws + OFF_HPRE);
  float* xh     = (float*)(ws + OFF_XH);
  float* act    = (float*)(ws + OFF_ACT);

  hipMemsetAsync(ws, 0, ZBYTES, stream);

  k_prep<<<258, 256, 0, stream>>>(w2, b2, Tt);
  k_prepw<<<32, 256, 0, stream>>>(w1, W1t);
  k_cnt<<<(E_EDGES + 255) / 256, 256, 0, stream>>>(ei, degI);
  k_scanA<<<NBLK_N, 256, 0, stream>>>(degI, bsum);
  k_scanB<<<1, 256, 0, stream>>>(bsum, bpre);
  k_scanC<<<NBLK_N, 256, 0, stream>>>(degI, bpre, rowptr, cursor);
  k_scatter<<<(E_EDGES + 255) / 256, 256, 0, stream>>>(ei, cursor, colsrc);
  k_nnconv<<<(E_EDGES + 255) / 256, 256, 0, stream>>>(x, ei, ea, W1t, b1, Tt, agg);
  k_root<<<NBLK_P, 256, 0, stream>>>(x, rootw, conv1b, agg, degI, hpre, rpart);
  k_fold1<<<1, 256, 0, stream>>>(rpart, n1w, n1b, gatw, gw2, tb);
  k_gatlin<<<NBLK_P, 256, 0, stream>>>(hpre, gw2, tb, attS, attD, xh, asrc, adst);
  k_gat<<<NBLK_P, 256, 0, stream>>>(rowptr, colsrc, xh, asrc, adst, gatb, act, gpart);
  k_fold2<<<1, 256, 0, stream>>>(gpart, n2w, n2b, linw, linb, wl);
  k_out<<<NGRAPH, 256, 0, stream>>>(act, wl, batch, (float*)d_out);
}

// Round 5
// 1168.660 us; speedup vs baseline: 2.1739x; 2.1739x over previous
//
#include <hip/hip_runtime.h>
#include <hip/hip_bf16.h>

#define N_NODES 50000
#define E_EDGES 300000
#define NGRAPH 64
#define KTOT 16512   // 1024*16 kf + 128 pad chunk (first 16 carry b2)
#define KC 128
#define NCHUNK 129
#define CSPLIT 65    // half 0: c in [0,65), half 1: c in [65,129)
#define NEGRP 1172   // ceil(E/256)
#define LNEPS 1e-5f
#define NBLK_N 196   // ceil(50000/256)
#define NBLK_P 12500 // N_NODES/4
// prescale so perm-truncate to bf16 ~= round-to-nearest (adds 0.375..0.75 ulp before trunc)
#define RPRE 1.00146484375f

typedef __bf16 bf16x8 __attribute__((ext_vector_type(8)));
typedef float floatx4 __attribute__((ext_vector_type(4)));
typedef float f32x2 __attribute__((ext_vector_type(2)));
typedef unsigned int u32x4 __attribute__((ext_vector_type(4)));

__device__ __forceinline__ void async_load16(const void* g, void* l) {
  __builtin_amdgcn_global_load_lds(
      (__attribute__((address_space(1))) void*)g,
      (__attribute__((address_space(3))) void*)l, 16, 0, 0);
}

// pack two f32 (pre-scaled) -> bf16x2 by truncation: 1 v_perm. lo16=bf16(p[0]), hi16=bf16(p[1])
__device__ __forceinline__ unsigned pkt(f32x2 p) {
  return __builtin_amdgcn_perm(__float_as_uint(p[1]), __float_as_uint(p[0]), 0x07060302u);
}
// pack two f32 -> bf16x2 with round-half-up: lo16=bf16(a), hi16=bf16(b)
__device__ __forceinline__ unsigned pkbf(float a, float b) {
  unsigned ua = __float_as_uint(a) + 0x8000u;
  unsigned ub = __float_as_uint(b) + 0x8000u;
  return __builtin_amdgcn_perm(ub, ua, 0x07060302u);
}

// ---------------- prep: Tt[h][kf] bf16 via LDS tile transpose ----------------
__global__ void k_prep(const float* __restrict__ w2, const float* __restrict__ b2,
                       __bf16* __restrict__ Tt) {
  __shared__ float tile[64][65];
  int t = threadIdx.x;
  int kf0 = blockIdx.x * 64;      // 258 blocks
  int r4 = t >> 6;
  int cc = t & 63;
#pragma unroll
  for (int p = 0; p < 16; ++p) {
    int row = p * 4 + r4;
    int kf = kf0 + row;
    float v = 0.f;
    if (kf < 16384) {
      int k = kf >> 4, f = kf & 15;
      v = w2[k * 1024 + f * 64 + cc];      // coalesced
    } else if (kf < 16400) {
      v = b2[(kf - 16384) * 64 + cc];
    }
    tile[row][cc] = v;
  }
  __syncthreads();
#pragma unroll
  for (int p = 0; p < 16; ++p) {
    int h = p * 4 + r4;
    Tt[(size_t)h * KTOT + kf0 + cc] = (__bf16)tile[cc][h];
  }
}

__global__ void k_prepw(const float* __restrict__ w1, float* __restrict__ W1t) {
  int i = blockIdx.x * 256 + threadIdx.x;
  if (i < 8192) { int k = i >> 3, j = i & 7; W1t[i] = w1[j * 1024 + k]; }
}

// ---------------- CSR build ----------------
__global__ void k_cnt(const int* __restrict__ ei, int* __restrict__ degI) {
  int e = blockIdx.x * 256 + threadIdx.x;
  if (e < E_EDGES) atomicAdd(&degI[ei[E_EDGES + e]], 1);
}

__global__ void k_scanA(const int* __restrict__ degI, int* __restrict__ bsum) {
  __shared__ int sm[256];
  int t = threadIdx.x;
  int i = blockIdx.x * 256 + t;
  sm[t] = (i < N_NODES) ? degI[i] : 0;
  __syncthreads();
  for (int off = 128; off > 0; off >>= 1) {
    if (t < off) sm[t] += sm[t + off];
    __syncthreads();
  }
  if (t == 0) bsum[blockIdx.x] = sm[0];
}

__global__ void k_scanB(const int* __restrict__ bsum, int* __restrict__ bpre) {
  __shared__ int s[256];
  int t = threadIdx.x;
  int v = (t < NBLK_N) ? bsum[t] : 0;
  s[t] = v;
  __syncthreads();
  for (int off = 1; off < 256; off <<= 1) {
    int add = (t >= off) ? s[t - off] : 0;
    __syncthreads();
    s[t] += add;
    __syncthreads();
  }
  if (t < NBLK_N) bpre[t] = s[t] - v;
}

__global__ void k_scanC(const int* __restrict__ degI, const int* __restrict__ bpre,
                        int* __restrict__ rowptr, int* __restrict__ cursor) {
  __shared__ int s[256];
  int t = threadIdx.x;
  int i = blockIdx.x * 256 + t;
  int d = (i < N_NODES) ? degI[i] : 0;
  s[t] = d;
  __syncthreads();
  for (int off = 1; off < 256; off <<= 1) {
    int add = (t >= off) ? s[t - off] : 0;
    __syncthreads();
    s[t] += add;
    __syncthreads();
  }
  int r = bpre[blockIdx.x] + s[t] - d;   // exclusive
  if (i < N_NODES) {
    rowptr[i] = r;
    cursor[i] = r;
    if (i == N_NODES - 1) rowptr[N_NODES] = r + d;
  }
}

__global__ void k_scatter(const int* __restrict__ ei, int* __restrict__ cursor,
                          int* __restrict__ colsrc) {
  int e = blockIdx.x * 256 + threadIdx.x;
  if (e < E_EDGES) {
    int s = ei[e], d = ei[E_EDGES + e];
    int pos = atomicAdd(&cursor[d], 1);
    colsrc[pos] = s;
  }
}

// ---------------- NNConv fused MFMA GEMM, split-K x2 ----------------
// block b: edge group (b>>1), K-half (b&1). NOTE: min-waves stays 3 —
// bounds(256,4) caps unified VGPR+AGPR at 128/wave and spills acc (R3: 6.9GB scratch traffic).
__global__ __launch_bounds__(256, 3)
void k_nnconv(const float* __restrict__ x, const int* __restrict__ ei,
              const float* __restrict__ ea, const float* __restrict__ W1t,
              const float* __restrict__ b1, const __bf16* __restrict__ Tt,
              float* __restrict__ agg) {
  __shared__ __align__(16) __bf16 sB[2][64 * KC];  // 32 KB
  __shared__ int sSrc[256];
  __shared__ int sDst[256];

  const int tid = threadIdx.x;
  const int wv = tid >> 6;
  const int lane = tid & 63;
  const int l15 = lane & 15;
  const int quad = lane >> 4;
  const int qxl = quad ^ l15;
  const bool qhi = (lane & 32) != 0;     // k_local = quad>>1: selects which r of the pair
  const int grp = blockIdx.x >> 1;
  const int half = blockIdx.x & 1;
  const int cstart = half ? CSPLIT : 0;
  const int cend = half ? NCHUNK : CSPLIT;
  const int base = grp * 256;

  int e = base + tid;
  bool valid = e < E_EDGES;
  sSrc[tid] = valid ? ei[e] : 0;
  sDst[tid] = valid ? ei[E_EDGES + e] : -1;

  f32x2 ea2[4];
  {
    const float4* p = (const float4*)(ea + (size_t)(valid ? e : 0) * 8);
    float4 a0 = p[0], a1 = p[1];
    ea2[0] = (f32x2){a0.x, a0.y};
    ea2[1] = (f32x2){a0.z, a0.w};
    ea2[2] = (f32x2){a1.x, a1.y};
    ea2[3] = (f32x2){a1.z, a1.w};
  }
  __syncthreads();

  // persistent pre-scaled x fragments (f32x2 pairs)
  const int f0 = (quad & 1) * 8;
  f32x2 xf2[4][4];
#pragma unroll
  for (int mb = 0; mb < 4; ++mb) {
    int el = wv * 64 + mb * 16 + l15;
    const float4* px = (const float4*)(x + (size_t)sSrc[el] * 16 + f0);
    float4 v0 = px[0], v1 = px[1];
    xf2[mb][0] = (f32x2){v0.x * RPRE, v0.y * RPRE};
    xf2[mb][1] = (f32x2){v0.z * RPRE, v0.w * RPRE};
    xf2[mb][2] = (f32x2){v1.x * RPRE, v1.y * RPRE};
    xf2[mb][3] = (f32x2){v1.z * RPRE, v1.w * RPRE};
  }

  // staging base: per-thread row/col fixed, advance KC elems per chunk.
  // cc uniform across it because it*16 = 0 (mod 16) in the h index.
  const int tidh = tid >> 4;
  const int ccsw = (tid & 15) ^ (tidh & 15);
  const __bf16* gbase = Tt + (size_t)tidh * KTOT + ccsw * 8 + cstart * KC;

  auto stageB = [&](int buf) {
    const __bf16* p = gbase;
#pragma unroll
    for (int it = 0; it < 4; ++it) {
      async_load16(p, &sB[buf][(it * 256 + tid) * 8]);
      p += 16 * KTOT;
    }
    gbase += KC;
  };

  unsigned prr[4];   // bf16-packed r pair per k-step: lo16=r[2ks], hi16=r[2ks+1]
  auto calcR = [&](int c, const float* w1p, const float* b1p) {
    if (c < 128) {   // uniform branch
#pragma unroll
      for (int ks = 0; ks < 4; ++ks) {
        float rv[2];
#pragma unroll
        for (int kk = 0; kk < 2; ++kk) {
          const f32x2* w = (const f32x2*)(w1p + (ks * 2 + kk) * 8);  // uniform -> s_load
          f32x2 s01 = ea2[0] * w[0] + ea2[1] * w[1];
          f32x2 s23 = ea2[2] * w[2] + ea2[3] * w[3];
          f32x2 s = s01 + s23;
          rv[kk] = fmaxf(b1p[ks * 2 + kk] + s[0] + s[1], 0.f);
        }
        prr[ks] = pkbf(rv[0], rv[1]);   // lo=r[2ks], hi=r[2ks+1]  (R4 bug: was swapped)
      }
    } else {
      prr[0] = 0x00003F80u;  // lo16 = bf16(1.0) at k=1024 (b2 row); rest 0
      prr[1] = prr[2] = prr[3] = 0u;
    }
  };

  floatx4 acc[4][4];
#pragma unroll
  for (int mb = 0; mb < 4; ++mb)
#pragma unroll
    for (int nb = 0; nb < 4; ++nb) acc[mb][nb] = floatx4{0.f, 0.f, 0.f, 0.f};

  stageB(0);
  calcR(cstart, W1t + cstart * 64, b1 + cstart * 8);
  const float* w1p = W1t + (cstart + 1) * 64;
  const float* b1p = b1 + (cstart + 1) * 8;
  int buf = 0;
  for (int c = cstart; c < cend; ++c) {
    __syncthreads();
    if (c + 1 < cend) stageB(buf ^ 1);
#pragma unroll
    for (int ks = 0; ks < 4; ++ks) {
      int t1 = qxl ^ (ks * 4);
      bf16x8 bfr[4];
#pragma unroll
      for (int nb = 0; nb < 4; ++nb)
        bfr[nb] = *(const bf16x8*)&sB[buf][(nb * 16 + l15) * KC + t1 * 8];
      unsigned pk0 = prr[ks];
#pragma unroll
      for (int mb = 0; mb < 4; ++mb) {
        unsigned u = (unsigned)__shfl((int)pk0, mb * 16 + l15);
        float rv = __uint_as_float(qhi ? (u & 0xffff0000u) : (u << 16));
        f32x2 rv2 = {rv, rv};
        u32x4 U;
        U[0] = pkt(rv2 * xf2[mb][0]);
        U[1] = pkt(rv2 * xf2[mb][1]);
        U[2] = pkt(rv2 * xf2[mb][2]);
        U[3] = pkt(rv2 * xf2[mb][3]);
        bf16x8 A = __builtin_bit_cast(bf16x8, U);
#pragma unroll
        for (int nb = 0; nb < 4; ++nb)
          acc[mb][nb] = __builtin_amdgcn_mfma_f32_16x16x32_bf16(A, bfr[nb], acc[mb][nb], 0, 0, 0);
      }
    }
    if (c + 1 < cend) {
      calcR(c + 1, w1p, b1p);  // wave-synchronous: shfls of prr above are done
      w1p += 64; b1p += 8;
    }
    buf ^= 1;
  }

  // epilogue: scatter partial msg to agg[dst]  (C layout: row=quad*4+reg, col=l15)
#pragma unroll
  for (int mb = 0; mb < 4; ++mb) {
    int el = wv * 64 + mb * 16 + quad * 4;
#pragma unroll
    for (int reg = 0; reg < 4; ++reg) {
      int dd = sDst[el + reg];
      if (dd >= 0) {
#pragma unroll
        for (int nb = 0; nb < 4; ++nb)
          atomicAdd(&agg[(size_t)dd * 64 + nb * 16 + l15], acc[mb][nb][reg]);
      }
    }
  }
}

// ---------------- h = relu(x@rootw + agg/deg + b); LN1 partials ----------------
__global__ void k_root(const float* __restrict__ x, const float* __restrict__ rootw,
                       const float* __restrict__ conv1b, const float* __restrict__ agg,
                       const int* __restrict__ degI, float* __restrict__ hpre,
                       float* __restrict__ rpart) {
  __shared__ float sW[1024];
  __shared__ float sx[64];
  __shared__ float red[8];
  int t = threadIdx.x;
  int blk = blockIdx.x;
#pragma unroll
  for (int i = 0; i < 4; ++i) sW[t + i * 256] = rootw[t + i * 256];
  if (t < 64) sx[t] = x[(size_t)blk * 64 + t];
  __syncthreads();
  int ln = t >> 6, h = t & 63;
  int n = blk * 4 + ln;
  float acc = conv1b[h];
#pragma unroll
  for (int f = 0; f < 16; ++f) acc += sx[ln * 16 + f] * sW[f * 64 + h];
  float dv = fmaxf((float)degI[n], 1.0f);
  float v = acc + agg[(size_t)n * 64 + h] / dv;
  v = fmaxf(v, 0.f);
  hpre[(size_t)n * 64 + h] = v;
  float s1 = v, s2 = v * v;
  for (int o = 32; o > 0; o >>= 1) { s1 += __shfl_down(s1, o); s2 += __shfl_down(s2, o); }
  if ((t & 63) == 0) { red[t >> 6] = s1; red[4 + (t >> 6)] = s2; }
  __syncthreads();
  if (t == 0) {
    rpart[blk * 2] = red[0] + red[1] + red[2] + red[3];
    rpart[blk * 2 + 1] = red[4] + red[5] + red[6] + red[7];
  }
}

// reduce LN1 partials; fold LN1 into gat_w
__global__ void k_fold1(const float* __restrict__ rpart, const float* __restrict__ n1w,
                        const float* __restrict__ n1b, const float* __restrict__ gatw,
                        float* __restrict__ gw2, float* __restrict__ tb) {
  __shared__ float red[8];
  __shared__ float sMI[2];
  __shared__ float sS[64], sT[64];
  int t = threadIdx.x;
  int wv = t >> 6, lane = t & 63;
  float a = 0.f, b = 0.f;
  for (int i = t; i < NBLK_P; i += 256) { a += rpart[2 * i]; b += rpart[2 * i + 1]; }
  for (int o = 32; o > 0; o >>= 1) { a += __shfl_down(a, o); b += __shfl_down(b, o); }
  if (lane == 0) { red[wv] = a; red[4 + wv] = b; }
  __syncthreads();
  if (t == 0) {
    float A = red[0] + red[1] + red[2] + red[3];
    float B = red[4] + red[5] + red[6] + red[7];
    const float M = (float)N_NODES * 64.f;
    float mu = A / M;
    float var = fmaxf(B / M - mu * mu, 0.f);
    sMI[0] = mu;
    sMI[1] = 1.f / (sqrtf(var) + LNEPS);
  }
  __syncthreads();
  if (t < 64) {
    float mu = sMI[0], inv = sMI[1];
    sS[t] = inv * n1w[t];
    sT[t] = n1b[t] - mu * inv * n1w[t];
  }
  __syncthreads();
  if (t < 64) {
    float acc = 0.f;
    for (int i = 0; i < 64; ++i) {
      float g = gatw[i * 64 + t];
      gw2[i * 64 + t] = sS[i] * g;
      acc += sT[i] * g;
    }
    tb[t] = acc;
  }
}

// xh = hpre@gw2 + tb ; attention scalars
__global__ void k_gatlin(const float* __restrict__ hpre, const float* __restrict__ gw2,
                         const float* __restrict__ tb, const float* __restrict__ attS,
                         const float* __restrict__ attD, float* __restrict__ xh,
                         float* __restrict__ asrc, float* __restrict__ adst) {
  __shared__ float sW[4096];
  __shared__ float sh[256];
  __shared__ float sxh[256];
  int t = threadIdx.x;
  int blk = blockIdx.x;
#pragma unroll
  for (int i = 0; i < 16; ++i) sW[t + i * 256] = gw2[t + i * 256];
  sh[t] = hpre[(size_t)blk * 256 + t];
  __syncthreads();
  int ln = t >> 6, h = t & 63;
  float acc = tb[h];
  for (int i = 0; i < 64; ++i) acc += sh[ln * 64 + i] * sW[i * 64 + h];
  xh[(size_t)blk * 256 + t] = acc;
  sxh[t] = acc;
  __syncthreads();
  if (t < 32) {
    int ln2 = t >> 3, rem = t & 7;
    int hd = rem & 3;
    const float* av = (rem >> 2) ? attD : attS;
    float a = 0.f;
#pragma unroll
    for (int d = 0; d < 16; ++d) a += sxh[ln2 * 64 + hd * 16 + d] * av[hd * 16 + d];
    int n = blk * 4 + ln2;
    if (rem >> 2) adst[n * 4 + hd] = a; else asrc[n * 4 + hd] = a;
  }
}

// ---------------- GAT: CSR gather, online softmax, fused relu + LN2 partials ----------------
__global__ void k_gat(const int* __restrict__ rowptr, const int* __restrict__ colsrc,
                      const float* __restrict__ xh, const float* __restrict__ asrc,
                      const float* __restrict__ adst, const float* __restrict__ gatb,
                      float* __restrict__ act, float* __restrict__ gpart) {
  __shared__ float sP[4][256];
  __shared__ int sS[4][64];
  __shared__ float sRed[8];
  int t = threadIdx.x;
  int wv = t >> 6, lane = t & 63;
  int n = blockIdx.x * 4 + wv;
  int start = rowptr[n], end = rowptr[n + 1];
  int deg = end - start;
  int myhd = lane >> 4;
  float ad[4];
#pragma unroll
  for (int hd = 0; hd < 4; ++hd) ad[hd] = adst[n * 4 + hd];
  float m[4] = {-1e30f, -1e30f, -1e30f, -1e30f};
  float l[4] = {0.f, 0.f, 0.f, 0.f};
  float O = 0.f;
  int items = deg + 1;  // + self loop
  for (int t0 = 0; t0 < items; t0 += 64) {
    int cnt = min(64, items - t0);
    int idx = t0 + lane;
    bool has = lane < cnt;
    int s = n;
    if (has && idx < deg) s = colsrc[start + idx];
    float a[4];
#pragma unroll
    for (int hd = 0; hd < 4; ++hd) {
      float av = has ? (asrc[s * 4 + hd] + ad[hd]) : -1e30f;
      a[hd] = (av > 0.f) ? av : 0.2f * av;  // leaky relu 0.2
    }
    float tm[4];
#pragma unroll
    for (int hd = 0; hd < 4; ++hd) tm[hd] = a[hd];
#pragma unroll
    for (int off = 32; off > 0; off >>= 1)
#pragma unroll
      for (int hd = 0; hd < 4; ++hd) tm[hd] = fmaxf(tm[hd], __shfl_xor(tm[hd], off));
    float p[4];
#pragma unroll
    for (int hd = 0; hd < 4; ++hd) {
      float mn = fmaxf(m[hd], tm[hd]);
      float sc = __expf(m[hd] - mn);
      l[hd] *= sc;
      if (hd == myhd) O *= sc;
      m[hd] = mn;
      p[hd] = has ? __expf(a[hd] - mn) : 0.f;
    }
    float ts[4];
#pragma unroll
    for (int hd = 0; hd < 4; ++hd) ts[hd] = p[hd];
#pragma unroll
    for (int off = 32; off > 0; off >>= 1)
#pragma unroll
      for (int hd = 0; hd < 4; ++hd) ts[hd] += __shfl_xor(ts[hd], off);
#pragma unroll
    for (int hd = 0; hd < 4; ++hd) l[hd] += ts[hd];
    sS[wv][lane] = s;
#pragma unroll
    for (int hd = 0; hd < 4; ++hd) sP[wv][lane * 4 + hd] = p[hd];
    // wave-private LDS region: program order suffices, no barrier
    for (int e2 = 0; e2 < cnt; ++e2) {
      int ss = sS[wv][e2];
      float pp = sP[wv][e2 * 4 + myhd];
      O = fmaf(pp, xh[(size_t)ss * 64 + lane], O);
    }
  }
  float lmy = (myhd & 2) ? ((myhd & 1) ? l[3] : l[2]) : ((myhd & 1) ? l[1] : l[0]);
  float outv = O / (lmy + 1e-16f);
  float v = fmaxf(outv + gatb[lane], 0.f);
  act[(size_t)n * 64 + lane] = v;
  float s1 = v, s2 = v * v;
#pragma unroll
  for (int off = 32; off > 0; off >>= 1) { s1 += __shfl_down(s1, off); s2 += __shfl_down(s2, off); }
  if (lane == 0) { sRed[wv] = s1; sRed[4 + wv] = s2; }
  __syncthreads();
  if (t == 0) {
    gpart[blockIdx.x * 2] = sRed[0] + sRed[1] + sRed[2] + sRed[3];
    gpart[blockIdx.x * 2 + 1] = sRed[4] + sRed[5] + sRed[6] + sRed[7];
  }
}

// reduce LN2 partials; fold LN2 + linear head into wl
__global__ void k_fold2(const float* __restrict__ gpart, const float* __restrict__ n2w,
                        const float* __restrict__ n2b, const float* __restrict__ linw,
                        const float* __restrict__ linb, float* __restrict__ wl) {
  __shared__ float red[8];
  __shared__ float sMI[2];
  int t = threadIdx.x;
  int wv = t >> 6, lane = t & 63;
  float a = 0.f, b = 0.f;
  for (int i = t; i < NBLK_P; i += 256) { a += gpart[2 * i]; b += gpart[2 * i + 1]; }
  for (int o = 32; o > 0; o >>= 1) { a += __shfl_down(a, o); b += __shfl_down(b, o); }
  if (lane == 0) { red[wv] = a; red[4 + wv] = b; }
  __syncthreads();
  if (t == 0) {
    float A = red[0] + red[1] + red[2] + red[3];
    float B = red[4] + red[5] + red[6] + red[7];
    const float M = (float)N_NODES * 64.f;
    float mu = A / M;
    float var = fmaxf(B / M - mu * mu, 0.f);
    sMI[0] = mu;
    sMI[1] = 1.f / (sqrtf(var) + LNEPS);
  }
  __syncthreads();
  if (t < 64) {
    float mu = sMI[0], inv = sMI[1];
    float w = inv * n2w[t] * linw[t];
    float p = (n2b[t] - mu * inv * n2w[t]) * linw[t];
    wl[t] = w;
    for (int o = 32; o > 0; o >>= 1) p += __shfl_down(p, o);
    if (t == 0) wl[64] = p + linb[0];
  }
}

// per-graph segmented pool + head (batch is sorted; zero atomics)
__global__ void k_out(const float* __restrict__ act, const float* __restrict__ wl,
                      const int* __restrict__ batch, float* __restrict__ out) {
  __shared__ float red[4];
  __shared__ float swl[64];
  int g = blockIdx.x;
  int t = threadIdx.x;
  int wv = t >> 6, lane = t & 63;
  if (t < 64) swl[t] = wl[t];
  __syncthreads();
  auto lbound = [&](int key) {
    int lo = 0, hi = N_NODES;
    while (lo < hi) { int mid = (lo + hi) >> 1; if (batch[mid] < key) lo = mid + 1; else hi = mid; }
    return lo;
  };
  int lo = lbound(g), hi = lbound(g + 1);
  int cntn = hi - lo;
  float s = 0.f;
  for (int idx = t; idx < cntn * 64; idx += 256) {
    int n = lo + (idx >> 6);
    int d = idx & 63;
    s += act[(size_t)n * 64 + d] * swl[d];
  }
  for (int o = 32; o > 0; o >>= 1) s += __shfl_down(s, o);
  if (lane == 0) red[wv] = s;
  __syncthreads();
  if (t == 0)
    out[g] = (red[0] + red[1] + red[2] + red[3]) / fmaxf((float)cntn, 1.f) + wl[64];
}

// ---------------- workspace layout (bytes, 64B aligned) ----------------
#define OFF_AGG     0UL
#define OFF_DEGI    12800000UL
#define ZBYTES      13000000UL
#define OFF_RPART   13000000UL
#define OFF_GPART   13100032UL
#define OFF_ROWPTR  13200064UL
#define OFF_CURSOR  13400128UL
#define OFF_BSUM    13600192UL
#define OFF_BPRE    13601024UL
#define OFF_COLSRC  13601856UL
#define OFF_TT      14801856UL
#define OFF_W1T     16915392UL
#define OFF_GW2     16948160UL
#define OFF_TB      16964544UL
#define OFF_WL      16964800UL
#define OFF_ASRC    16965120UL
#define OFF_ADST    17765120UL
#define OFF_HPRE    18565120UL
#define OFF_XH      31365120UL
#define OFF_ACT     44165120UL
#define WS_NEED     56965120UL

extern "C" void kernel_launch(void* const* d_in, const int* in_sizes, int n_in,
                              void* d_out, int out_size, void* d_ws, size_t ws_size,
                              hipStream_t stream) {
  const float* x = (const float*)d_in[0];
  const int* ei = (const int*)d_in[1];
  const float* ea = (const float*)d_in[2];
  const int* batch = (const int*)d_in[3];
  const float* w1 = (const float*)d_in[4];
  const float* b1 = (const float*)d_in[5];
  const float* w2 = (const float*)d_in[6];
  const float* b2 = (const float*)d_in[7];
  const float* rootw = (const float*)d_in[8];
  const float* conv1b = (const float*)d_in[9];
  const float* n1w = (const float*)d_in[10];
  const float* n1b = (const float*)d_in[11];
  const float* gatw = (const float*)d_in[12];
  const float* attS = (const float*)d_in[13];
  const float* attD = (const float*)d_in[14];
  const float* gatb = (const float*)d_in[15];
  const float* n2w = (const float*)d_in[16];
  const float* n2b = (const float*)d_in[17];
  const float* linw = (const float*)d_in[18];
  const float* linb = (const float*)d_in[19];

  if (ws_size < WS_NEED) return;
  char* ws = (char*)d_ws;
  float* agg    = (float*)(ws + OFF_AGG);
  int* degI     = (int*)(ws + OFF_DEGI);
  float* rpart  = (float*)(ws + OFF_RPART);
  float* gpart  = (float*)(ws + OFF_GPART);
  int* rowptr   = (int*)(ws + OFF_ROWPTR);
  int* cursor   = (int*)(ws + OFF_CURSOR);
  int* bsum     = (int*)(ws + OFF_BSUM);
  int* bpre     = (int*)(ws + OFF_BPRE);
  int* colsrc   = (int*)(ws + OFF_COLSRC);
  __bf16* Tt    = (__bf16*)(ws + OFF_TT);
  float* W1t    = (float*)(ws + OFF_W1T);
  float* gw2    = (float*)(ws + OFF_GW2);
  float* tb     = (float*)(ws + OFF_TB);
  float* wl     = (float*)(ws + OFF_WL);
  float* asrc   = (float*)(ws + OFF_ASRC);
  float* adst   = (float*)(ws + OFF_ADST);
  float* hpre   = (float*)(ws + OFF_HPRE);
  float* xh     = (float*)(ws + OFF_XH);
  float* act    = (float*)(ws + OFF_ACT);

  hipMemsetAsync(ws, 0, ZBYTES, stream);

  k_prep<<<258, 256, 0, stream>>>(w2, b2, Tt);
  k_prepw<<<32, 256, 0, stream>>>(w1, W1t);
  k_cnt<<<(E_EDGES + 255) / 256, 256, 0, stream>>>(ei, degI);
  k_scanA<<<NBLK_N, 256, 0, stream>>>(degI, bsum);
  k_scanB<<<1, 256, 0, stream>>>(bsum, bpre);
  k_scanC<<<NBLK_N, 256, 0, stream>>>(degI, bpre, rowptr, cursor);
  k_scatter<<<(E_EDGES + 255) / 256, 256, 0, stream>>>(ei, cursor, colsrc);
  k_nnconv<<<NEGRP * 2, 256, 0, stream>>>(x, ei, ea, W1t, b1, Tt, agg);
  k_root<<<NBLK_P, 256, 0, stream>>>(x, rootw, conv1b, agg, degI, hpre, rpart);
  k_fold1<<<1, 256, 0, stream>>>(rpart, n1w, n1b, gatw, gw2, tb);
  k_gatlin<<<NBLK_P, 256, 0, stream>>>(hpre, gw2, tb, attS, attD, xh, asrc, adst);
  k_gat<<<NBLK_P, 256, 0, stream>>>(rowptr, colsrc, xh, asrc, adst, gatb, act, gpart);
  k_fold2<<<1, 256, 0, stream>>>(gpart, n2w, n2b, linw, linb, wl);
  k_out<<<NGRAPH, 256, 0, stream>>>(act, wl, batch, (float*)d_out);
}

// Round 6
// 1111.525 us; speedup vs baseline: 2.2856x; 1.0514x over previous
//
#include <hip/hip_runtime.h>
#include <hip/hip_bf16.h>

#define N_NODES 50000
#define E_EDGES 300000
#define NGRAPH 64
#define KTOT 16512   // 1024*16 kf + 128 pad chunk (first 16 carry b2)
#define KC 128
#define NCHUNK 129
#define CSPLIT 65    // half 0: c in [0,65), half 1: c in [65,129)
#define NEGRP 1172   // ceil(E/256)
#define LNEPS 1e-5f
#define NBLK_N 196   // ceil(50000/256)
#define NBLK_P 12500 // N_NODES/4
// prescale so perm-truncate to bf16 ~= round-to-nearest (adds 0.375..0.75 ulp before trunc)
#define RPRE 1.00146484375f

typedef __bf16 bf16x8 __attribute__((ext_vector_type(8)));
typedef float floatx4 __attribute__((ext_vector_type(4)));
typedef float f32x2 __attribute__((ext_vector_type(2)));
typedef unsigned int u32x4 __attribute__((ext_vector_type(4)));

__device__ __forceinline__ void async_load16(const void* g, void* l) {
  __builtin_amdgcn_global_load_lds(
      (__attribute__((address_space(1))) void*)g,
      (__attribute__((address_space(3))) void*)l, 16, 0, 0);
}

// pack two f32 (pre-scaled) -> bf16x2 by truncation: 1 v_perm. lo16=bf16(p[0]), hi16=bf16(p[1])
__device__ __forceinline__ unsigned pkt(f32x2 p) {
  return __builtin_amdgcn_perm(__float_as_uint(p[1]), __float_as_uint(p[0]), 0x07060302u);
}
// pack two f32 -> bf16x2 with round-half-up: lo16=bf16(a), hi16=bf16(b)
__device__ __forceinline__ unsigned pkbf(float a, float b) {
  unsigned ua = __float_as_uint(a) + 0x8000u;
  unsigned ub = __float_as_uint(b) + 0x8000u;
  return __builtin_amdgcn_perm(ub, ua, 0x07060302u);
}

// ---------------- prep: Tt[h][kf] bf16 via LDS tile transpose ----------------
__global__ void k_prep(const float* __restrict__ w2, const float* __restrict__ b2,
                       __bf16* __restrict__ Tt) {
  __shared__ float tile[64][65];
  int t = threadIdx.x;
  int kf0 = blockIdx.x * 64;      // 258 blocks
  int r4 = t >> 6;
  int cc = t & 63;
#pragma unroll
  for (int p = 0; p < 16; ++p) {
    int row = p * 4 + r4;
    int kf = kf0 + row;
    float v = 0.f;
    if (kf < 16384) {
      int k = kf >> 4, f = kf & 15;
      v = w2[k * 1024 + f * 64 + cc];      // coalesced
    } else if (kf < 16400) {
      v = b2[(kf - 16384) * 64 + cc];
    }
    tile[row][cc] = v;
  }
  __syncthreads();
#pragma unroll
  for (int p = 0; p < 16; ++p) {
    int h = p * 4 + r4;
    Tt[(size_t)h * KTOT + kf0 + cc] = (__bf16)tile[cc][h];
  }
}

__global__ void k_prepw(const float* __restrict__ w1, float* __restrict__ W1t) {
  int i = blockIdx.x * 256 + threadIdx.x;
  if (i < 8192) { int k = i >> 3, j = i & 7; W1t[i] = w1[j * 1024 + k]; }
}

// ---------------- CSR build ----------------
__global__ void k_cnt(const int* __restrict__ ei, int* __restrict__ degI) {
  int e = blockIdx.x * 256 + threadIdx.x;
  if (e < E_EDGES) atomicAdd(&degI[ei[E_EDGES + e]], 1);
}

__global__ void k_scanA(const int* __restrict__ degI, int* __restrict__ bsum) {
  __shared__ int sm[256];
  int t = threadIdx.x;
  int i = blockIdx.x * 256 + t;
  sm[t] = (i < N_NODES) ? degI[i] : 0;
  __syncthreads();
  for (int off = 128; off > 0; off >>= 1) {
    if (t < off) sm[t] += sm[t + off];
    __syncthreads();
  }
  if (t == 0) bsum[blockIdx.x] = sm[0];
}

__global__ void k_scanB(const int* __restrict__ bsum, int* __restrict__ bpre) {
  __shared__ int s[256];
  int t = threadIdx.x;
  int v = (t < NBLK_N) ? bsum[t] : 0;
  s[t] = v;
  __syncthreads();
  for (int off = 1; off < 256; off <<= 1) {
    int add = (t >= off) ? s[t - off] : 0;
    __syncthreads();
    s[t] += add;
    __syncthreads();
  }
  if (t < NBLK_N) bpre[t] = s[t] - v;
}

__global__ void k_scanC(const int* __restrict__ degI, const int* __restrict__ bpre,
                        int* __restrict__ rowptr, int* __restrict__ cursor) {
  __shared__ int s[256];
  int t = threadIdx.x;
  int i = blockIdx.x * 256 + t;
  int d = (i < N_NODES) ? degI[i] : 0;
  s[t] = d;
  __syncthreads();
  for (int off = 1; off < 256; off <<= 1) {
    int add = (t >= off) ? s[t - off] : 0;
    __syncthreads();
    s[t] += add;
    __syncthreads();
  }
  int r = bpre[blockIdx.x] + s[t] - d;   // exclusive
  if (i < N_NODES) {
    rowptr[i] = r;
    cursor[i] = r;
    if (i == N_NODES - 1) rowptr[N_NODES] = r + d;
  }
}

__global__ void k_scatter(const int* __restrict__ ei, int* __restrict__ cursor,
                          int* __restrict__ colsrc) {
  int e = blockIdx.x * 256 + threadIdx.x;
  if (e < E_EDGES) {
    int s = ei[e], d = ei[E_EDGES + e];
    int pos = atomicAdd(&cursor[d], 1);
    colsrc[pos] = s;
  }
}

// ---------------- NNConv fused MFMA GEMM, split-K x2, r-pipeline decoupled ----------------
// block b: edge group (b>>1), K-half (b&1). min-waves stays 3 (R3: (256,4) spills acc).
// R6: all r work for chunk c+1 (SMEM calcR + 16 bpermutes) runs AFTER chunk c's MFMAs;
// bpermute latency is absorbed by the barrier drain; extraction is 1 v_perm per value.
__global__ __launch_bounds__(256, 3)
void k_nnconv(const float* __restrict__ x, const int* __restrict__ ei,
              const float* __restrict__ ea, const float* __restrict__ W1t,
              const float* __restrict__ b1, const __bf16* __restrict__ Tt,
              float* __restrict__ agg) {
  __shared__ __align__(16) __bf16 sB[2][64 * KC];  // 32 KB
  __shared__ int sSrc[256];
  __shared__ int sDst[256];

  const int tid = threadIdx.x;
  const int wv = tid >> 6;
  const int lane = tid & 63;
  const int l15 = lane & 15;
  const int quad = lane >> 4;
  const int qxl = quad ^ l15;
  const bool qhi = (lane & 32) != 0;     // k_local = quad>>1: selects which r of the pair
  // extract selector: rv(f32) = bf16 in hi16, zeros low. pool: bytes4-7=src0(u), 0-3=src1(0)
  const unsigned rsel = qhi ? 0x07060100u : 0x05040100u;
  const int grp = blockIdx.x >> 1;
  const int half = blockIdx.x & 1;
  const int cstart = half ? CSPLIT : 0;
  const int cend = half ? NCHUNK : CSPLIT;
  const int base = grp * 256;

  int e = base + tid;
  bool valid = e < E_EDGES;
  sSrc[tid] = valid ? ei[e] : 0;
  sDst[tid] = valid ? ei[E_EDGES + e] : -1;

  f32x2 ea2[4];
  {
    const float4* p = (const float4*)(ea + (size_t)(valid ? e : 0) * 8);
    float4 a0 = p[0], a1 = p[1];
    ea2[0] = (f32x2){a0.x, a0.y};
    ea2[1] = (f32x2){a0.z, a0.w};
    ea2[2] = (f32x2){a1.x, a1.y};
    ea2[3] = (f32x2){a1.z, a1.w};
  }
  __syncthreads();

  // persistent pre-scaled x fragments (f32x2 pairs)
  const int f0 = (quad & 1) * 8;
  f32x2 xf2[4][4];
#pragma unroll
  for (int mb = 0; mb < 4; ++mb) {
    int el = wv * 64 + mb * 16 + l15;
    const float4* px = (const float4*)(x + (size_t)sSrc[el] * 16 + f0);
    float4 v0 = px[0], v1 = px[1];
    xf2[mb][0] = (f32x2){v0.x * RPRE, v0.y * RPRE};
    xf2[mb][1] = (f32x2){v0.z * RPRE, v0.w * RPRE};
    xf2[mb][2] = (f32x2){v1.x * RPRE, v1.y * RPRE};
    xf2[mb][3] = (f32x2){v1.z * RPRE, v1.w * RPRE};
  }

  // bpermute byte addresses for r broadcast (lane mb*16+l15)
  int bpaddr[4];
#pragma unroll
  for (int mb = 0; mb < 4; ++mb) bpaddr[mb] = (mb * 16 + l15) * 4;

  // staging base: per-thread row/col fixed, advance KC elems per chunk.
  const int tidh = tid >> 4;
  const int ccsw = (tid & 15) ^ (tidh & 15);
  const __bf16* gbase = Tt + (size_t)tidh * KTOT + ccsw * 8 + cstart * KC;

  auto stageB = [&](int buf) {
    const __bf16* p = gbase;
#pragma unroll
    for (int it = 0; it < 4; ++it) {
      async_load16(p, &sB[buf][(it * 256 + tid) * 8]);
      p += 16 * KTOT;
    }
    gbase += KC;
  };

  unsigned prr[4];   // bf16-packed r pair per k-step: lo16=r[2ks], hi16=r[2ks+1]
  auto calcR = [&](int c, const float* w1p, const float* b1p) {
    if (c < 128) {   // uniform branch
#pragma unroll
      for (int ks = 0; ks < 4; ++ks) {
        float rv[2];
#pragma unroll
        for (int kk = 0; kk < 2; ++kk) {
          const f32x2* w = (const f32x2*)(w1p + (ks * 2 + kk) * 8);  // uniform -> s_load
          f32x2 s01 = ea2[0] * w[0] + ea2[1] * w[1];
          f32x2 s23 = ea2[2] * w[2] + ea2[3] * w[3];
          f32x2 s = s01 + s23;
          rv[kk] = fmaxf(b1p[ks * 2 + kk] + s[0] + s[1], 0.f);
        }
        prr[ks] = pkbf(rv[0], rv[1]);   // lo=r[2ks], hi=r[2ks+1]
      }
    } else {
      prr[0] = 0x00003F80u;  // lo16 = bf16(1.0) at k=1024 (b2 row); rest 0
      prr[1] = prr[2] = prr[3] = 0u;
    }
  };

  unsigned ubuf[16]; // bpermuted r pairs for the NEXT chunk, [ks*4+mb]
  auto bcastR = [&]() {
#pragma unroll
    for (int ks = 0; ks < 4; ++ks)
#pragma unroll
      for (int mb = 0; mb < 4; ++mb)
        ubuf[ks * 4 + mb] = (unsigned)__builtin_amdgcn_ds_bpermute(bpaddr[mb], (int)prr[ks]);
  };

  floatx4 acc[4][4];
#pragma unroll
  for (int mb = 0; mb < 4; ++mb)
#pragma unroll
    for (int nb = 0; nb < 4; ++nb) acc[mb][nb] = floatx4{0.f, 0.f, 0.f, 0.f};

  stageB(0);
  calcR(cstart, W1t + cstart * 64, b1 + cstart * 8);
  bcastR();
  const float* w1p = W1t + (cstart + 1) * 64;
  const float* b1p = b1 + (cstart + 1) * 8;
  int buf = 0;
  for (int c = cstart; c < cend; ++c) {
    __syncthreads();
    if (c + 1 < cend) stageB(buf ^ 1);
    // extract this chunk's r values: 1 v_perm each, no memory deps
    float rvc[16];
#pragma unroll
    for (int i = 0; i < 16; ++i)
      rvc[i] = __uint_as_float(__builtin_amdgcn_perm(ubuf[i], 0u, rsel));
    // MFMA phase: only ds_read(B)->MFMA chains remain
#pragma unroll
    for (int ks = 0; ks < 4; ++ks) {
      int t1 = qxl ^ (ks * 4);
      bf16x8 bfr[4];
#pragma unroll
      for (int nb = 0; nb < 4; ++nb)
        bfr[nb] = *(const bf16x8*)&sB[buf][(nb * 16 + l15) * KC + t1 * 8];
#pragma unroll
      for (int mb = 0; mb < 4; ++mb) {
        float rv = rvc[ks * 4 + mb];
        f32x2 rv2 = {rv, rv};
        u32x4 U;
        U[0] = pkt(rv2 * xf2[mb][0]);
        U[1] = pkt(rv2 * xf2[mb][1]);
        U[2] = pkt(rv2 * xf2[mb][2]);
        U[3] = pkt(rv2 * xf2[mb][3]);
        bf16x8 A = __builtin_bit_cast(bf16x8, U);
#pragma unroll
        for (int nb = 0; nb < 4; ++nb)
          acc[mb][nb] = __builtin_amdgcn_mfma_f32_16x16x32_bf16(A, bfr[nb], acc[mb][nb], 0, 0, 0);
      }
    }
    // r pipeline for chunk c+1: SMEM after MFMAs, bpermutes drained by next barrier
    if (c + 1 < cend) {
      calcR(c + 1, w1p, b1p);
      bcastR();
      w1p += 64; b1p += 8;
    }
    buf ^= 1;
  }

  // epilogue: scatter partial msg to agg[dst]  (C layout: row=quad*4+reg, col=l15)
#pragma unroll
  for (int mb = 0; mb < 4; ++mb) {
    int el = wv * 64 + mb * 16 + quad * 4;
#pragma unroll
    for (int reg = 0; reg < 4; ++reg) {
      int dd = sDst[el + reg];
      if (dd >= 0) {
#pragma unroll
        for (int nb = 0; nb < 4; ++nb)
          atomicAdd(&agg[(size_t)dd * 64 + nb * 16 + l15], acc[mb][nb][reg]);
      }
    }
  }
}

// ---------------- h = relu(x@rootw + agg/deg + b); LN1 partials ----------------
__global__ void k_root(const float* __restrict__ x, const float* __restrict__ rootw,
                       const float* __restrict__ conv1b, const float* __restrict__ agg,
                       const int* __restrict__ degI, float* __restrict__ hpre,
                       float* __restrict__ rpart) {
  __shared__ float sW[1024];
  __shared__ float sx[64];
  __shared__ float red[8];
  int t = threadIdx.x;
  int blk = blockIdx.x;
#pragma unroll
  for (int i = 0; i < 4; ++i) sW[t + i * 256] = rootw[t + i * 256];
  if (t < 64) sx[t] = x[(size_t)blk * 64 + t];
  __syncthreads();
  int ln = t >> 6, h = t & 63;
  int n = blk * 4 + ln;
  float acc = conv1b[h];
#pragma unroll
  for (int f = 0; f < 16; ++f) acc += sx[ln * 16 + f] * sW[f * 64 + h];
  float dv = fmaxf((float)degI[n], 1.0f);
  float v = acc + agg[(size_t)n * 64 + h] / dv;
  v = fmaxf(v, 0.f);
  hpre[(size_t)n * 64 + h] = v;
  float s1 = v, s2 = v * v;
  for (int o = 32; o > 0; o >>= 1) { s1 += __shfl_down(s1, o); s2 += __shfl_down(s2, o); }
  if ((t & 63) == 0) { red[t >> 6] = s1; red[4 + (t >> 6)] = s2; }
  __syncthreads();
  if (t == 0) {
    rpart[blk * 2] = red[0] + red[1] + red[2] + red[3];
    rpart[blk * 2 + 1] = red[4] + red[5] + red[6] + red[7];
  }
}

// reduce LN1 partials; fold LN1 into gat_w
__global__ void k_fold1(const float* __restrict__ rpart, const float* __restrict__ n1w,
                        const float* __restrict__ n1b, const float* __restrict__ gatw,
                        float* __restrict__ gw2, float* __restrict__ tb) {
  __shared__ float red[8];
  __shared__ float sMI[2];
  __shared__ float sS[64], sT[64];
  int t = threadIdx.x;
  int wv = t >> 6, lane = t & 63;
  float a = 0.f, b = 0.f;
  for (int i = t; i < NBLK_P; i += 256) { a += rpart[2 * i]; b += rpart[2 * i + 1]; }
  for (int o = 32; o > 0; o >>= 1) { a += __shfl_down(a, o); b += __shfl_down(b, o); }
  if (lane == 0) { red[wv] = a; red[4 + wv] = b; }
  __syncthreads();
  if (t == 0) {
    float A = red[0] + red[1] + red[2] + red[3];
    float B = red[4] + red[5] + red[6] + red[7];
    const float M = (float)N_NODES * 64.f;
    float mu = A / M;
    float var = fmaxf(B / M - mu * mu, 0.f);
    sMI[0] = mu;
    sMI[1] = 1.f / (sqrtf(var) + LNEPS);
  }
  __syncthreads();
  if (t < 64) {
    float mu = sMI[0], inv = sMI[1];
    sS[t] = inv * n1w[t];
    sT[t] = n1b[t] - mu * inv * n1w[t];
  }
  __syncthreads();
  if (t < 64) {
    float acc = 0.f;
    for (int i = 0; i < 64; ++i) {
      float g = gatw[i * 64 + t];
      gw2[i * 64 + t] = sS[i] * g;
      acc += sT[i] * g;
    }
    tb[t] = acc;
  }
}

// xh = hpre@gw2 + tb ; attention scalars
__global__ void k_gatlin(const float* __restrict__ hpre, const float* __restrict__ gw2,
                         const float* __restrict__ tb, const float* __restrict__ attS,
                         const float* __restrict__ attD, float* __restrict__ xh,
                         float* __restrict__ asrc, float* __restrict__ adst) {
  __shared__ float sW[4096];
  __shared__ float sh[256];
  __shared__ float sxh[256];
  int t = threadIdx.x;
  int blk = blockIdx.x;
#pragma unroll
  for (int i = 0; i < 16; ++i) sW[t + i * 256] = gw2[t + i * 256];
  sh[t] = hpre[(size_t)blk * 256 + t];
  __syncthreads();
  int ln = t >> 6, h = t & 63;
  float acc = tb[h];
  for (int i = 0; i < 64; ++i) acc += sh[ln * 64 + i] * sW[i * 64 + h];
  xh[(size_t)blk * 256 + t] = acc;
  sxh[t] = acc;
  __syncthreads();
  if (t < 32) {
    int ln2 = t >> 3, rem = t & 7;
    int hd = rem & 3;
    const float* av = (rem >> 2) ? attD : attS;
    float a = 0.f;
#pragma unroll
    for (int d = 0; d < 16; ++d) a += sxh[ln2 * 64 + hd * 16 + d] * av[hd * 16 + d];
    int n = blk * 4 + ln2;
    if (rem >> 2) adst[n * 4 + hd] = a; else asrc[n * 4 + hd] = a;
  }
}

// ---------------- GAT: CSR gather, online softmax, fused relu + LN2 partials ----------------
__global__ void k_gat(const int* __restrict__ rowptr, const int* __restrict__ colsrc,
                      const float* __restrict__ xh, const float* __restrict__ asrc,
                      const float* __restrict__ adst, const float* __restrict__ gatb,
                      float* __restrict__ act, float* __restrict__ gpart) {
  __shared__ float sP[4][256];
  __shared__ int sS[4][64];
  __shared__ float sRed[8];
  int t = threadIdx.x;
  int wv = t >> 6, lane = t & 63;
  int n = blockIdx.x * 4 + wv;
  int start = rowptr[n], end = rowptr[n + 1];
  int deg = end - start;
  int myhd = lane >> 4;
  float ad[4];
#pragma unroll
  for (int hd = 0; hd < 4; ++hd) ad[hd] = adst[n * 4 + hd];
  float m[4] = {-1e30f, -1e30f, -1e30f, -1e30f};
  float l[4] = {0.f, 0.f, 0.f, 0.f};
  float O = 0.f;
  int items = deg + 1;  // + self loop
  for (int t0 = 0; t0 < items; t0 += 64) {
    int cnt = min(64, items - t0);
    int idx = t0 + lane;
    bool has = lane < cnt;
    int s = n;
    if (has && idx < deg) s = colsrc[start + idx];
    float a[4];
#pragma unroll
    for (int hd = 0; hd < 4; ++hd) {
      float av = has ? (asrc[s * 4 + hd] + ad[hd]) : -1e30f;
      a[hd] = (av > 0.f) ? av : 0.2f * av;  // leaky relu 0.2
    }
    float tm[4];
#pragma unroll
    for (int hd = 0; hd < 4; ++hd) tm[hd] = a[hd];
#pragma unroll
    for (int off = 32; off > 0; off >>= 1)
#pragma unroll
      for (int hd = 0; hd < 4; ++hd) tm[hd] = fmaxf(tm[hd], __shfl_xor(tm[hd], off));
    float p[4];
#pragma unroll
    for (int hd = 0; hd < 4; ++hd) {
      float mn = fmaxf(m[hd], tm[hd]);
      float sc = __expf(m[hd] - mn);
      l[hd] *= sc;
      if (hd == myhd) O *= sc;
      m[hd] = mn;
      p[hd] = has ? __expf(a[hd] - mn) : 0.f;
    }
    float ts[4];
#pragma unroll
    for (int hd = 0; hd < 4; ++hd) ts[hd] = p[hd];
#pragma unroll
    for (int off = 32; off > 0; off >>= 1)
#pragma unroll
      for (int hd = 0; hd < 4; ++hd) ts[hd] += __shfl_xor(ts[hd], off);
#pragma unroll
    for (int hd = 0; hd < 4; ++hd) l[hd] += ts[hd];
    sS[wv][lane] = s;
#pragma unroll
    for (int hd = 0; hd < 4; ++hd) sP[wv][lane * 4 + hd] = p[hd];
    // wave-private LDS region: program order suffices, no barrier
    for (int e2 = 0; e2 < cnt; ++e2) {
      int ss = sS[wv][e2];
      float pp = sP[wv][e2 * 4 + myhd];
      O = fmaf(pp, xh[(size_t)ss * 64 + lane], O);
    }
  }
  float lmy = (myhd & 2) ? ((myhd & 1) ? l[3] : l[2]) : ((myhd & 1) ? l[1] : l[0]);
  float outv = O / (lmy + 1e-16f);
  float v = fmaxf(outv + gatb[lane], 0.f);
  act[(size_t)n * 64 + lane] = v;
  float s1 = v, s2 = v * v;
#pragma unroll
  for (int off = 32; off > 0; off >>= 1) { s1 += __shfl_down(s1, off); s2 += __shfl_down(s2, off); }
  if (lane == 0) { sRed[wv] = s1; sRed[4 + wv] = s2; }
  __syncthreads();
  if (t == 0) {
    gpart[blockIdx.x * 2] = sRed[0] + sRed[1] + sRed[2] + sRed[3];
    gpart[blockIdx.x * 2 + 1] = sRed[4] + sRed[5] + sRed[6] + sRed[7];
  }
}

// reduce LN2 partials; fold LN2 + linear head into wl
__global__ void k_fold2(const float* __restrict__ gpart, const float* __restrict__ n2w,
                        const float* __restrict__ n2b, const float* __restrict__ linw,
                        const float* __restrict__ linb, float* __restrict__ wl) {
  __shared__ float red[8];
  __shared__ float sMI[2];
  int t = threadIdx.x;
  int wv = t >> 6, lane = t & 63;
  float a = 0.f, b = 0.f;
  for (int i = t; i < NBLK_P; i += 256) { a += gpart[2 * i]; b += gpart[2 * i + 1]; }
  for (int o = 32; o > 0; o >>= 1) { a += __shfl_down(a, o); b += __shfl_down(b, o); }
  if (lane == 0) { red[wv] = a; red[4 + wv] = b; }
  __syncthreads();
  if (t == 0) {
    float A = red[0] + red[1] + red[2] + red[3];
    float B = red[4] + red[5] + red[6] + red[7];
    const float M = (float)N_NODES * 64.f;
    float mu = A / M;
    float var = fmaxf(B / M - mu * mu, 0.f);
    sMI[0] = mu;
    sMI[1] = 1.f / (sqrtf(var) + LNEPS);
  }
  __syncthreads();
  if (t < 64) {
    float mu = sMI[0], inv = sMI[1];
    float w = inv * n2w[t] * linw[t];
    float p = (n2b[t] - mu * inv * n2w[t]) * linw[t];
    wl[t] = w;
    for (int o = 32; o > 0; o >>= 1) p += __shfl_down(p, o);
    if (t == 0) wl[64] = p + linb[0];
  }
}

// per-graph segmented pool + head (batch is sorted; zero atomics)
__global__ void k_out(const float* __restrict__ act, const float* __restrict__ wl,
                      const int* __restrict__ batch, float* __restrict__ out) {
  __shared__ float red[4];
  __shared__ float swl[64];
  int g = blockIdx.x;
  int t = threadIdx.x;
  int wv = t >> 6, lane = t & 63;
  if (t < 64) swl[t] = wl[t];
  __syncthreads();
  auto lbound = [&](int key) {
    int lo = 0, hi = N_NODES;
    while (lo < hi) { int mid = (lo + hi) >> 1; if (batch[mid] < key) lo = mid + 1; else hi = mid; }
    return lo;
  };
  int lo = lbound(g), hi = lbound(g + 1);
  int cntn = hi - lo;
  float s = 0.f;
  for (int idx = t; idx < cntn * 64; idx += 256) {
    int n = lo + (idx >> 6);
    int d = idx & 63;
    s += act[(size_t)n * 64 + d] * swl[d];
  }
  for (int o = 32; o > 0; o >>= 1) s += __shfl_down(s, o);
  if (lane == 0) red[wv] = s;
  __syncthreads();
  if (t == 0)
    out[g] = (red[0] + red[1] + red[2] + red[3]) / fmaxf((float)cntn, 1.f) + wl[64];
}

// ---------------- workspace layout (bytes, 64B aligned) ----------------
#define OFF_AGG     0UL
#define OFF_DEGI    12800000UL
#define ZBYTES      13000000UL
#define OFF_RPART   13000000UL
#define OFF_GPART   13100032UL
#define OFF_ROWPTR  13200064UL
#define OFF_CURSOR  13400128UL
#define OFF_BSUM    13600192UL
#define OFF_BPRE    13601024UL
#define OFF_COLSRC  13601856UL
#define OFF_TT      14801856UL
#define OFF_W1T     16915392UL
#define OFF_GW2     16948160UL
#define OFF_TB      16964544UL
#define OFF_WL      16964800UL
#define OFF_ASRC    16965120UL
#define OFF_ADST    17765120UL
#define OFF_HPRE    18565120UL
#define OFF_XH      31365120UL
#define OFF_ACT     44165120UL
#define WS_NEED     56965120UL

extern "C" void kernel_launch(void* const* d_in, const int* in_sizes, int n_in,
                              void* d_out, int out_size, void* d_ws, size_t ws_size,
                              hipStream_t stream) {
  const float* x = (const float*)d_in[0];
  const int* ei = (const int*)d_in[1];
  const float* ea = (const float*)d_in[2];
  const int* batch = (const int*)d_in[3];
  const float* w1 = (const float*)d_in[4];
  const float* b1 = (const float*)d_in[5];
  const float* w2 = (const float*)d_in[6];
  const float* b2 = (const float*)d_in[7];
  const float* rootw = (const float*)d_in[8];
  const float* conv1b = (const float*)d_in[9];
  const float* n1w = (const float*)d_in[10];
  const float* n1b = (const float*)d_in[11];
  const float* gatw = (const float*)d_in[12];
  const float* attS = (const float*)d_in[13];
  const float* attD = (const float*)d_in[14];
  const float* gatb = (const float*)d_in[15];
  const float* n2w = (const float*)d_in[16];
  const float* n2b = (const float*)d_in[17];
  const float* linw = (const float*)d_in[18];
  const float* linb = (const float*)d_in[19];

  if (ws_size < WS_NEED) return;
  char* ws = (char*)d_ws;
  float* agg    = (float*)(ws + OFF_AGG);
  int* degI     = (int*)(ws + OFF_DEGI);
  float* rpart  = (float*)(ws + OFF_RPART);
  float* gpart  = (float*)(ws + OFF_GPART);
  int* rowptr   = (int*)(ws + OFF_ROWPTR);
  int* cursor   = (int*)(ws + OFF_CURSOR);
  int* bsum     = (int*)(ws + OFF_BSUM);
  int* bpre     = (int*)(ws + OFF_BPRE);
  int* colsrc   = (int*)(ws + OFF_COLSRC);
  __bf16* Tt    = (__bf16*)(ws + OFF_TT);
  float* W1t    = (float*)(ws + OFF_W1T);
  float* gw2    = (float*)(ws + OFF_GW2);
  float* tb     = (float*)(ws + OFF_TB);
  float* wl     = (float*)(ws + OFF_WL);
  float* asrc   = (float*)(ws + OFF_ASRC);
  float* adst   = (float*)(ws + OFF_ADST);
  float* hpre   = (float*)(ws + OFF_HPRE);
  float* xh     = (float*)(ws + OFF_XH);
  float* act    = (float*)(ws + OFF_ACT);

  hipMemsetAsync(ws, 0, ZBYTES, stream);

  k_prep<<<258, 256, 0, stream>>>(w2, b2, Tt);
  k_prepw<<<32, 256, 0, stream>>>(w1, W1t);
  k_cnt<<<(E_EDGES + 255) / 256, 256, 0, stream>>>(ei, degI);
  k_scanA<<<NBLK_N, 256, 0, stream>>>(degI, bsum);
  k_scanB<<<1, 256, 0, stream>>>(bsum, bpre);
  k_scanC<<<NBLK_N, 256, 0, stream>>>(degI, bpre, rowptr, cursor);
  k_scatter<<<(E_EDGES + 255) / 256, 256, 0, stream>>>(ei, cursor, colsrc);
  k_nnconv<<<NEGRP * 2, 256, 0, stream>>>(x, ei, ea, W1t, b1, Tt, agg);
  k_root<<<NBLK_P, 256, 0, stream>>>(x, rootw, conv1b, agg, degI, hpre, rpart);
  k_fold1<<<1, 256, 0, stream>>>(rpart, n1w, n1b, gatw, gw2, tb);
  k_gatlin<<<NBLK_P, 256, 0, stream>>>(hpre, gw2, tb, attS, attD, xh, asrc, adst);
  k_gat<<<NBLK_P, 256, 0, stream>>>(rowptr, colsrc, xh, asrc, adst, gatb, act, gpart);
  k_fold2<<<1, 256, 0, stream>>>(gpart, n2w, n2b, linw, linb, wl);
  k_out<<<NGRAPH, 256, 0, stream>>>(act, wl, batch, (float*)d_out);
}

// Round 7
// 1033.748 us; speedup vs baseline: 2.4576x; 1.0752x over previous
//
#include <hip/hip_runtime.h>
#include <hip/hip_bf16.h>

#define N_NODES 50000
#define E_EDGES 300000
#define NGRAPH 64
#define KTOT 16512   // 1024*16 kf + 112 zero-pad + 16 b2 rows (kf 16384..16399)
#define NCHUNK 129
#define CSPLIT 65    // half 0: c in [0,65), half 1: c in [65,129)
#define NSTEP 516    // NCHUNK*4 (one step = 32 kf)
#define NEGRP 1172   // ceil(E/256)
#define LNEPS 1e-5f
#define NBLK_N 196   // ceil(50000/256)
#define NBLK_P 12500 // N_NODES/4
// prescale so perm-truncate to bf16 ~= round-to-nearest (adds 0.375..0.75 ulp before trunc)
#define RPRE 1.00146484375f

typedef __bf16 bf16x8 __attribute__((ext_vector_type(8)));
typedef float floatx4 __attribute__((ext_vector_type(4)));
typedef float f32x2 __attribute__((ext_vector_type(2)));
typedef unsigned int u32x4 __attribute__((ext_vector_type(4)));

// pack two f32 (pre-scaled) -> bf16x2 by truncation: 1 v_perm. lo16=bf16(p[0]), hi16=bf16(p[1])
__device__ __forceinline__ unsigned pkt(f32x2 p) {
  return __builtin_amdgcn_perm(__float_as_uint(p[1]), __float_as_uint(p[0]), 0x07060302u);
}
// pack two f32 -> bf16x2 with round-half-up: lo16=bf16(a), hi16=bf16(b)
__device__ __forceinline__ unsigned pkbf(float a, float b) {
  unsigned ua = __float_as_uint(a) + 0x8000u;
  unsigned ub = __float_as_uint(b) + 0x8000u;
  return __builtin_amdgcn_perm(ub, ua, 0x07060302u);
}

// ---------------- prep: Tt2[step][h][kw] bf16, step=kf>>5, kw=kf&31 ----------------
// one-time 2MB build; read pattern uncoalesced but L2-absorbed.
__global__ void k_prep(const float* __restrict__ w2, const float* __restrict__ b2,
                       __bf16* __restrict__ Tt2) {
  int idx = blockIdx.x * 256 + threadIdx.x;   // 4144 blocks cover (NSTEP+1)*2048
  int step = idx >> 11;
  int rem = idx & 2047;
  int h = rem >> 5;
  int kw = rem & 31;
  int kf = step * 32 + kw;
  float v = 0.f;
  if (kf < 16384) {
    int k = kf >> 4, f = kf & 15;
    v = w2[k * 1024 + f * 64 + h];
  } else if (kf < 16400) {
    v = b2[(kf - 16384) * 64 + h];
  }
  Tt2[idx] = (__bf16)v;
}

__global__ void k_prepw(const float* __restrict__ w1, float* __restrict__ W1t) {
  int i = blockIdx.x * 256 + threadIdx.x;
  if (i < 8192) { int k = i >> 3, j = i & 7; W1t[i] = w1[j * 1024 + k]; }
}

// ---------------- CSR build ----------------
__global__ void k_cnt(const int* __restrict__ ei, int* __restrict__ degI) {
  int e = blockIdx.x * 256 + threadIdx.x;
  if (e < E_EDGES) atomicAdd(&degI[ei[E_EDGES + e]], 1);
}

__global__ void k_scanA(const int* __restrict__ degI, int* __restrict__ bsum) {
  __shared__ int sm[256];
  int t = threadIdx.x;
  int i = blockIdx.x * 256 + t;
  sm[t] = (i < N_NODES) ? degI[i] : 0;
  __syncthreads();
  for (int off = 128; off > 0; off >>= 1) {
    if (t < off) sm[t] += sm[t + off];
    __syncthreads();
  }
  if (t == 0) bsum[blockIdx.x] = sm[0];
}

__global__ void k_scanB(const int* __restrict__ bsum, int* __restrict__ bpre) {
  __shared__ int s[256];
  int t = threadIdx.x;
  int v = (t < NBLK_N) ? bsum[t] : 0;
  s[t] = v;
  __syncthreads();
  for (int off = 1; off < 256; off <<= 1) {
    int add = (t >= off) ? s[t - off] : 0;
    __syncthreads();
    s[t] += add;
    __syncthreads();
  }
  if (t < NBLK_N) bpre[t] = s[t] - v;
}

__global__ void k_scanC(const int* __restrict__ degI, const int* __restrict__ bpre,
                        int* __restrict__ rowptr, int* __restrict__ cursor) {
  __shared__ int s[256];
  int t = threadIdx.x;
  int i = blockIdx.x * 256 + t;
  int d = (i < N_NODES) ? degI[i] : 0;
  s[t] = d;
  __syncthreads();
  for (int off = 1; off < 256; off <<= 1) {
    int add = (t >= off) ? s[t - off] : 0;
    __syncthreads();
    s[t] += add;
    __syncthreads();
  }
  int r = bpre[blockIdx.x] + s[t] - d;   // exclusive
  if (i < N_NODES) {
    rowptr[i] = r;
    cursor[i] = r;
    if (i == N_NODES - 1) rowptr[N_NODES] = r + d;
  }
}

__global__ void k_scatter(const int* __restrict__ ei, int* __restrict__ cursor,
                          int* __restrict__ colsrc) {
  int e = blockIdx.x * 256 + threadIdx.x;
  if (e < E_EDGES) {
    int s = ei[e], d = ei[E_EDGES + e];
    int pos = atomicAdd(&cursor[d], 1);
    colsrc[pos] = s;
  }
}

// ---------------- NNConv fused MFMA GEMM, split-K x2, register-direct B ----------------
// R7: B fragments load straight from L2-resident Tt2 into VGPRs (coalesced 4KB/step/wave),
// 2-deep register double-buffer over the (c,ks) stream -> waits are vmcnt(4)-style, never 0.
// ZERO LDS, ZERO barriers: src/dst/r move via shfl/bpermute (wave-local).
// min-waves 3 (R3: (256,4) spills acc). Spill canary: WRITE_SIZE >> 154MB.
__global__ __launch_bounds__(256, 3)
void k_nnconv(const float* __restrict__ x, const int* __restrict__ ei,
              const float* __restrict__ ea, const float* __restrict__ W1t,
              const float* __restrict__ b1, const __bf16* __restrict__ Tt2,
              float* __restrict__ agg) {
  const int tid = threadIdx.x;
  const int lane = tid & 63;
  const int l15 = lane & 15;
  const int quad = lane >> 4;
  const bool qhi = (lane & 32) != 0;     // k_local = quad>>1: selects which r of the pair
  // extract selector: rv(f32) = bf16 in hi16, zeros low. bytes4-7=src0(u), 0-3=src1(0)
  const unsigned rsel = qhi ? 0x07060100u : 0x05040100u;
  const int grp = blockIdx.x >> 1;
  const int half = blockIdx.x & 1;
  const int cstart = half ? CSPLIT : 0;
  const int cend = half ? NCHUNK : CSPLIT;

  int e = grp * 256 + tid;
  bool valid = e < E_EDGES;
  int srcv = valid ? ei[e] : 0;
  int dstv = valid ? ei[E_EDGES + e] : -1;

  f32x2 ea2[4];
  {
    const float4* p = (const float4*)(ea + (size_t)(valid ? e : 0) * 8);
    float4 a0 = p[0], a1 = p[1];
    ea2[0] = (f32x2){a0.x, a0.y};
    ea2[1] = (f32x2){a0.z, a0.w};
    ea2[2] = (f32x2){a1.x, a1.y};
    ea2[3] = (f32x2){a1.z, a1.w};
  }

  // persistent pre-scaled x fragments via shfl of srcv (no LDS)
  const int f0 = (quad & 1) * 8;
  f32x2 xf2[4][4];
#pragma unroll
  for (int mb = 0; mb < 4; ++mb) {
    int s = __shfl(srcv, mb * 16 + l15);
    const float4* px = (const float4*)(x + (size_t)s * 16 + f0);
    float4 v0 = px[0], v1 = px[1];
    xf2[mb][0] = (f32x2){v0.x * RPRE, v0.y * RPRE};
    xf2[mb][1] = (f32x2){v0.z * RPRE, v0.w * RPRE};
    xf2[mb][2] = (f32x2){v1.x * RPRE, v1.y * RPRE};
    xf2[mb][3] = (f32x2){v1.z * RPRE, v1.w * RPRE};
  }

  // bpermute byte addresses for r broadcast (lane mb*16+l15)
  int bpaddr[4];
#pragma unroll
  for (int mb = 0; mb < 4; ++mb) bpaddr[mb] = (mb * 16 + l15) * 4;

  // B stream pointer: per-lane offset inside a [64h][32kw] step-tile
  const __bf16* bp = Tt2 + (size_t)(cstart * 4) * 2048 + (l15 * 32 + quad * 8);

  bf16x8 Ba[4], Bb[4];
  auto loadB = [&](bf16x8* d) {
    d[0] = *(const bf16x8*)(bp);
    d[1] = *(const bf16x8*)(bp + 512);
    d[2] = *(const bf16x8*)(bp + 1024);
    d[3] = *(const bf16x8*)(bp + 1536);
    bp += 2048;
  };

  unsigned prr[4];   // bf16-packed r pair per k-step: lo16=r[2ks], hi16=r[2ks+1]
  auto calcR = [&](int c, const float* w1p, const float* b1p) {
    if (c < 128) {   // uniform branch
#pragma unroll
      for (int ks = 0; ks < 4; ++ks) {
        float rv[2];
#pragma unroll
        for (int kk = 0; kk < 2; ++kk) {
          const f32x2* w = (const f32x2*)(w1p + (ks * 2 + kk) * 8);  // uniform -> s_load
          f32x2 s01 = ea2[0] * w[0] + ea2[1] * w[1];
          f32x2 s23 = ea2[2] * w[2] + ea2[3] * w[3];
          f32x2 s = s01 + s23;
          rv[kk] = fmaxf(b1p[ks * 2 + kk] + s[0] + s[1], 0.f);
        }
        prr[ks] = pkbf(rv[0], rv[1]);   // lo=r[2ks], hi=r[2ks+1]
      }
    } else {
      prr[0] = 0x00003F80u;  // lo16 = bf16(1.0) at k=1024 (b2 rows); rest 0
      prr[1] = prr[2] = prr[3] = 0u;
    }
  };

  unsigned ubuf[16]; // bpermuted r pairs for the CURRENT chunk, [ks*4+mb]
  auto bcastR = [&]() {
#pragma unroll
    for (int ks = 0; ks < 4; ++ks)
#pragma unroll
      for (int mb = 0; mb < 4; ++mb)
        ubuf[ks * 4 + mb] = (unsigned)__builtin_amdgcn_ds_bpermute(bpaddr[mb], (int)prr[ks]);
  };

  floatx4 acc[4][4];
#pragma unroll
  for (int mb = 0; mb < 4; ++mb)
#pragma unroll
    for (int nb = 0; nb < 4; ++nb) acc[mb][nb] = floatx4{0.f, 0.f, 0.f, 0.f};

  calcR(cstart, W1t + cstart * 64, b1 + cstart * 8);
  bcastR();
  loadB(Ba);
  const float* w1p = W1t + (cstart + 1) * 64;
  const float* b1p = b1 + (cstart + 1) * 8;

  for (int c = cstart; c < cend; ++c) {
#pragma unroll
    for (int ks = 0; ks < 4; ++ks) {
      bf16x8* Bc = (ks & 1) ? Bb : Ba;
      bf16x8* Bn = (ks & 1) ? Ba : Bb;
      loadB(Bn);   // prefetch next step (final step reads the zero pad tile)
#pragma unroll
      for (int mb = 0; mb < 4; ++mb) {
        float rv = __uint_as_float(__builtin_amdgcn_perm(ubuf[ks * 4 + mb], 0u, rsel));
        f32x2 rv2 = {rv, rv};
        u32x4 U;
        U[0] = pkt(rv2 * xf2[mb][0]);
        U[1] = pkt(rv2 * xf2[mb][1]);
        U[2] = pkt(rv2 * xf2[mb][2]);
        U[3] = pkt(rv2 * xf2[mb][3]);
        bf16x8 A = __builtin_bit_cast(bf16x8, U);
#pragma unroll
        for (int nb = 0; nb < 4; ++nb)
          acc[mb][nb] = __builtin_amdgcn_mfma_f32_16x16x32_bf16(A, Bc[nb], acc[mb][nb], 0, 0, 0);
      }
    }
    if (c + 1 < cend) {
      calcR(c + 1, w1p, b1p);   // wave-synchronous; bpermutes wave-local
      bcastR();
      w1p += 64; b1p += 8;
    }
  }

  // epilogue: scatter partial msg to agg[dst]  (C layout: row=quad*4+reg, col=l15)
#pragma unroll
  for (int mb = 0; mb < 4; ++mb) {
#pragma unroll
    for (int reg = 0; reg < 4; ++reg) {
      int dd = __shfl(dstv, mb * 16 + quad * 4 + reg);
      if (dd >= 0) {
#pragma unroll
        for (int nb = 0; nb < 4; ++nb)
          atomicAdd(&agg[(size_t)dd * 64 + nb * 16 + l15], acc[mb][nb][reg]);
      }
    }
  }
}

// ---------------- h = relu(x@rootw + agg/deg + b); LN1 partials ----------------
__global__ void k_root(const float* __restrict__ x, const float* __restrict__ rootw,
                       const float* __restrict__ conv1b, const float* __restrict__ agg,
                       const int* __restrict__ degI, float* __restrict__ hpre,
                       float* __restrict__ rpart) {
  __shared__ float sW[1024];
  __shared__ float sx[64];
  __shared__ float red[8];
  int t = threadIdx.x;
  int blk = blockIdx.x;
#pragma unroll
  for (int i = 0; i < 4; ++i) sW[t + i * 256] = rootw[t + i * 256];
  if (t < 64) sx[t] = x[(size_t)blk * 64 + t];
  __syncthreads();
  int ln = t >> 6, h = t & 63;
  int n = blk * 4 + ln;
  float acc = conv1b[h];
#pragma unroll
  for (int f = 0; f < 16; ++f) acc += sx[ln * 16 + f] * sW[f * 64 + h];
  float dv = fmaxf((float)degI[n], 1.0f);
  float v = acc + agg[(size_t)n * 64 + h] / dv;
  v = fmaxf(v, 0.f);
  hpre[(size_t)n * 64 + h] = v;
  float s1 = v, s2 = v * v;
  for (int o = 32; o > 0; o >>= 1) { s1 += __shfl_down(s1, o); s2 += __shfl_down(s2, o); }
  if ((t & 63) == 0) { red[t >> 6] = s1; red[4 + (t >> 6)] = s2; }
  __syncthreads();
  if (t == 0) {
    rpart[blk * 2] = red[0] + red[1] + red[2] + red[3];
    rpart[blk * 2 + 1] = red[4] + red[5] + red[6] + red[7];
  }
}

// reduce LN1 partials; fold LN1 into gat_w
__global__ void k_fold1(const float* __restrict__ rpart, const float* __restrict__ n1w,
                        const float* __restrict__ n1b, const float* __restrict__ gatw,
                        float* __restrict__ gw2, float* __restrict__ tb) {
  __shared__ float red[8];
  __shared__ float sMI[2];
  __shared__ float sS[64], sT[64];
  int t = threadIdx.x;
  int wv = t >> 6, lane = t & 63;
  float a = 0.f, b = 0.f;
  for (int i = t; i < NBLK_P; i += 256) { a += rpart[2 * i]; b += rpart[2 * i + 1]; }
  for (int o = 32; o > 0; o >>= 1) { a += __shfl_down(a, o); b += __shfl_down(b, o); }
  if (lane == 0) { red[wv] = a; red[4 + wv] = b; }
  __syncthreads();
  if (t == 0) {
    float A = red[0] + red[1] + red[2] + red[3];
    float B = red[4] + red[5] + red[6] + red[7];
    const float M = (float)N_NODES * 64.f;
    float mu = A / M;
    float var = fmaxf(B / M - mu * mu, 0.f);
    sMI[0] = mu;
    sMI[1] = 1.f / (sqrtf(var) + LNEPS);
  }
  __syncthreads();
  if (t < 64) {
    float mu = sMI[0], inv = sMI[1];
    sS[t] = inv * n1w[t];
    sT[t] = n1b[t] - mu * inv * n1w[t];
  }
  __syncthreads();
  if (t < 64) {
    float acc = 0.f;
    for (int i = 0; i < 64; ++i) {
      float g = gatw[i * 64 + t];
      gw2[i * 64 + t] = sS[i] * g;
      acc += sT[i] * g;
    }
    tb[t] = acc;
  }
}

// xh = hpre@gw2 + tb ; attention scalars
__global__ void k_gatlin(const float* __restrict__ hpre, const float* __restrict__ gw2,
                         const float* __restrict__ tb, const float* __restrict__ attS,
                         const float* __restrict__ attD, float* __restrict__ xh,
                         float* __restrict__ asrc, float* __restrict__ adst) {
  __shared__ float sW[4096];
  __shared__ float sh[256];
  __shared__ float sxh[256];
  int t = threadIdx.x;
  int blk = blockIdx.x;
#pragma unroll
  for (int i = 0; i < 16; ++i) sW[t + i * 256] = gw2[t + i * 256];
  sh[t] = hpre[(size_t)blk * 256 + t];
  __syncthreads();
  int ln = t >> 6, h = t & 63;
  float acc = tb[h];
  for (int i = 0; i < 64; ++i) acc += sh[ln * 64 + i] * sW[i * 64 + h];
  xh[(size_t)blk * 256 + t] = acc;
  sxh[t] = acc;
  __syncthreads();
  if (t < 32) {
    int ln2 = t >> 3, rem = t & 7;
    int hd = rem & 3;
    const float* av = (rem >> 2) ? attD : attS;
    float a = 0.f;
#pragma unroll
    for (int d = 0; d < 16; ++d) a += sxh[ln2 * 64 + hd * 16 + d] * av[hd * 16 + d];
    int n = blk * 4 + ln2;
    if (rem >> 2) adst[n * 4 + hd] = a; else asrc[n * 4 + hd] = a;
  }
}

// ---------------- GAT: CSR gather, online softmax, fused relu + LN2 partials ----------------
__global__ void k_gat(const int* __restrict__ rowptr, const int* __restrict__ colsrc,
                      const float* __restrict__ xh, const float* __restrict__ asrc,
                      const float* __restrict__ adst, const float* __restrict__ gatb,
                      float* __restrict__ act, float* __restrict__ gpart) {
  __shared__ float sP[4][256];
  __shared__ int sS[4][64];
  __shared__ float sRed[8];
  int t = threadIdx.x;
  int wv = t >> 6, lane = t & 63;
  int n = blockIdx.x * 4 + wv;
  int start = rowptr[n], end = rowptr[n + 1];
  int deg = end - start;
  int myhd = lane >> 4;
  float ad[4];
#pragma unroll
  for (int hd = 0; hd < 4; ++hd) ad[hd] = adst[n * 4 + hd];
  float m[4] = {-1e30f, -1e30f, -1e30f, -1e30f};
  float l[4] = {0.f, 0.f, 0.f, 0.f};
  float O = 0.f;
  int items = deg + 1;  // + self loop
  for (int t0 = 0; t0 < items; t0 += 64) {
    int cnt = min(64, items - t0);
    int idx = t0 + lane;
    bool has = lane < cnt;
    int s = n;
    if (has && idx < deg) s = colsrc[start + idx];
    float a[4];
#pragma unroll
    for (int hd = 0; hd < 4; ++hd) {
      float av = has ? (asrc[s * 4 + hd] + ad[hd]) : -1e30f;
      a[hd] = (av > 0.f) ? av : 0.2f * av;  // leaky relu 0.2
    }
    float tm[4];
#pragma unroll
    for (int hd = 0; hd < 4; ++hd) tm[hd] = a[hd];
#pragma unroll
    for (int off = 32; off > 0; off >>= 1)
#pragma unroll
      for (int hd = 0; hd < 4; ++hd) tm[hd] = fmaxf(tm[hd], __shfl_xor(tm[hd], off));
    float p[4];
#pragma unroll
    for (int hd = 0; hd < 4; ++hd) {
      float mn = fmaxf(m[hd], tm[hd]);
      float sc = __expf(m[hd] - mn);
      l[hd] *= sc;
      if (hd == myhd) O *= sc;
      m[hd] = mn;
      p[hd] = has ? __expf(a[hd] - mn) : 0.f;
    }
    float ts[4];
#pragma unroll
    for (int hd = 0; hd < 4; ++hd) ts[hd] = p[hd];
#pragma unroll
    for (int off = 32; off > 0; off >>= 1)
#pragma unroll
      for (int hd = 0; hd < 4; ++hd) ts[hd] += __shfl_xor(ts[hd], off);
#pragma unroll
    for (int hd = 0; hd < 4; ++hd) l[hd] += ts[hd];
    sS[wv][lane] = s;
#pragma unroll
    for (int hd = 0; hd < 4; ++hd) sP[wv][lane * 4 + hd] = p[hd];
    // wave-private LDS region: program order suffices, no barrier
    for (int e2 = 0; e2 < cnt; ++e2) {
      int ss = sS[wv][e2];
      float pp = sP[wv][e2 * 4 + myhd];
      O = fmaf(pp, xh[(size_t)ss * 64 + lane], O);
    }
  }
  float lmy = (myhd & 2) ? ((myhd & 1) ? l[3] : l[2]) : ((myhd & 1) ? l[1] : l[0]);
  float outv = O / (lmy + 1e-16f);
  float v = fmaxf(outv + gatb[lane], 0.f);
  act[(size_t)n * 64 + lane] = v;
  float s1 = v, s2 = v * v;
#pragma unroll
  for (int off = 32; off > 0; off >>= 1) { s1 += __shfl_down(s1, off); s2 += __shfl_down(s2, off); }
  if (lane == 0) { sRed[wv] = s1; sRed[4 + wv] = s2; }
  __syncthreads();
  if (t == 0) {
    gpart[blockIdx.x * 2] = sRed[0] + sRed[1] + sRed[2] + sRed[3];
    gpart[blockIdx.x * 2 + 1] = sRed[4] + sRed[5] + sRed[6] + sRed[7];
  }
}

// reduce LN2 partials; fold LN2 + linear head into wl
__global__ void k_fold2(const float* __restrict__ gpart, const float* __restrict__ n2w,
                        const float* __restrict__ n2b, const float* __restrict__ linw,
                        const float* __restrict__ linb, float* __restrict__ wl) {
  __shared__ float red[8];
  __shared__ float sMI[2];
  int t = threadIdx.x;
  int wv = t >> 6, lane = t & 63;
  float a = 0.f, b = 0.f;
  for (int i = t; i < NBLK_P; i += 256) { a += gpart[2 * i]; b += gpart[2 * i + 1]; }
  for (int o = 32; o > 0; o >>= 1) { a += __shfl_down(a, o); b += __shfl_down(b, o); }
  if (lane == 0) { red[wv] = a; red[4 + wv] = b; }
  __syncthreads();
  if (t == 0) {
    float A = red[0] + red[1] + red[2] + red[3];
    float B = red[4] + red[5] + red[6] + red[7];
    const float M = (float)N_NODES * 64.f;
    float mu = A / M;
    float var = fmaxf(B / M - mu * mu, 0.f);
    sMI[0] = mu;
    sMI[1] = 1.f / (sqrtf(var) + LNEPS);
  }
  __syncthreads();
  if (t < 64) {
    float mu = sMI[0], inv = sMI[1];
    float w = inv * n2w[t] * linw[t];
    float p = (n2b[t] - mu * inv * n2w[t]) * linw[t];
    wl[t] = w;
    for (int o = 32; o > 0; o >>= 1) p += __shfl_down(p, o);
    if (t == 0) wl[64] = p + linb[0];
  }
}

// per-graph segmented pool + head (batch is sorted; zero atomics)
__global__ void k_out(const float* __restrict__ act, const float* __restrict__ wl,
                      const int* __restrict__ batch, float* __restrict__ out) {
  __shared__ float red[4];
  __shared__ float swl[64];
  int g = blockIdx.x;
  int t = threadIdx.x;
  int wv = t >> 6, lane = t & 63;
  if (t < 64) swl[t] = wl[t];
  __syncthreads();
  auto lbound = [&](int key) {
    int lo = 0, hi = N_NODES;
    while (lo < hi) { int mid = (lo + hi) >> 1; if (batch[mid] < key) lo = mid + 1; else hi = mid; }
    return lo;
  };
  int lo = lbound(g), hi = lbound(g + 1);
  int cntn = hi - lo;
  float s = 0.f;
  for (int idx = t; idx < cntn * 64; idx += 256) {
    int n = lo + (idx >> 6);
    int d = idx & 63;
    s += act[(size_t)n * 64 + d] * swl[d];
  }
  for (int o = 32; o > 0; o >>= 1) s += __shfl_down(s, o);
  if (lane == 0) red[wv] = s;
  __syncthreads();
  if (t == 0)
    out[g] = (red[0] + red[1] + red[2] + red[3]) / fmaxf((float)cntn, 1.f) + wl[64];
}

// ---------------- workspace layout (bytes, 64B aligned) ----------------
#define OFF_AGG     0UL
#define OFF_DEGI    12800000UL
#define ZBYTES      13000000UL
#define OFF_RPART   13000000UL
#define OFF_GPART   13100032UL
#define OFF_ROWPTR  13200064UL
#define OFF_CURSOR  13400128UL
#define OFF_BSUM    13600192UL
#define OFF_BPRE    13601024UL
#define OFF_COLSRC  13601856UL
#define OFF_TT      14801856UL   // (NSTEP+1)*2048*2 = 2117632 (incl. zero pad step)
#define OFF_W1T     16919488UL
#define OFF_GW2     16952256UL
#define OFF_TB      16968640UL
#define OFF_WL      16968896UL
#define OFF_ASRC    16969216UL
#define OFF_ADST    17769216UL
#define OFF_HPRE    18569216UL
#define OFF_XH      31369216UL
#define OFF_ACT     44169216UL
#define WS_NEED     56969216UL

extern "C" void kernel_launch(void* const* d_in, const int* in_sizes, int n_in,
                              void* d_out, int out_size, void* d_ws, size_t ws_size,
                              hipStream_t stream) {
  const float* x = (const float*)d_in[0];
  const int* ei = (const int*)d_in[1];
  const float* ea = (const float*)d_in[2];
  const int* batch = (const int*)d_in[3];
  const float* w1 = (const float*)d_in[4];
  const float* b1 = (const float*)d_in[5];
  const float* w2 = (const float*)d_in[6];
  const float* b2 = (const float*)d_in[7];
  const float* rootw = (const float*)d_in[8];
  const float* conv1b = (const float*)d_in[9];
  const float* n1w = (const float*)d_in[10];
  const float* n1b = (const float*)d_in[11];
  const float* gatw = (const float*)d_in[12];
  const float* attS = (const float*)d_in[13];
  const float* attD = (const float*)d_in[14];
  const float* gatb = (const float*)d_in[15];
  const float* n2w = (const float*)d_in[16];
  const float* n2b = (const float*)d_in[17];
  const float* linw = (const float*)d_in[18];
  const float* linb = (const float*)d_in[19];

  if (ws_size < WS_NEED) return;
  char* ws = (char*)d_ws;
  float* agg    = (float*)(ws + OFF_AGG);
  int* degI     = (int*)(ws + OFF_DEGI);
  float* rpart  = (float*)(ws + OFF_RPART);
  float* gpart  = (float*)(ws + OFF_GPART);
  int* rowptr   = (int*)(ws + OFF_ROWPTR);
  int* cursor   = (int*)(ws + OFF_CURSOR);
  int* bsum     = (int*)(ws + OFF_BSUM);
  int* bpre     = (int*)(ws + OFF_BPRE);
  int* colsrc   = (int*)(ws + OFF_COLSRC);
  __bf16* Tt2   = (__bf16*)(ws + OFF_TT);
  float* W1t    = (float*)(ws + OFF_W1T);
  float* gw2    = (float*)(ws + OFF_GW2);
  float* tb     = (float*)(ws + OFF_TB);
  float* wl     = (float*)(ws + OFF_WL);
  float* asrc   = (float*)(ws + OFF_ASRC);
  float* adst   = (float*)(ws + OFF_ADST);
  float* hpre   = (float*)(ws + OFF_HPRE);
  float* xh     = (float*)(ws + OFF_XH);
  float* act    = (float*)(ws + OFF_ACT);

  hipMemsetAsync(ws, 0, ZBYTES, stream);

  k_prep<<<(NSTEP + 1) * 8, 256, 0, stream>>>(w2, b2, Tt2);   // (516+1)*2048/256
  k_prepw<<<32, 256, 0, stream>>>(w1, W1t);
  k_cnt<<<(E_EDGES + 255) / 256, 256, 0, stream>>>(ei, degI);
  k_scanA<<<NBLK_N, 256, 0, stream>>>(degI, bsum);
  k_scanB<<<1, 256, 0, stream>>>(bsum, bpre);
  k_scanC<<<NBLK_N, 256, 0, stream>>>(degI, bpre, rowptr, cursor);
  k_scatter<<<(E_EDGES + 255) / 256, 256, 0, stream>>>(ei, cursor, colsrc);
  k_nnconv<<<NEGRP * 2, 256, 0, stream>>>(x, ei, ea, W1t, b1, Tt2, agg);
  k_root<<<NBLK_P, 256, 0, stream>>>(x, rootw, conv1b, agg, degI, hpre, rpart);
  k_fold1<<<1, 256, 0, stream>>>(rpart, n1w, n1b, gatw, gw2, tb);
  k_gatlin<<<NBLK_P, 256, 0, stream>>>(hpre, gw2, tb, attS, attD, xh, asrc, adst);
  k_gat<<<NBLK_P, 256, 0, stream>>>(rowptr, colsrc, xh, asrc, adst, gatb, act, gpart);
  k_fold2<<<1, 256, 0, stream>>>(gpart, n2w, n2b, linw, linb, wl);
  k_out<<<NGRAPH, 256, 0, stream>>>(act, wl, batch, (float*)d_out);
}

// Round 8
// 1011.531 us; speedup vs baseline: 2.5116x; 1.0220x over previous
//
#include <hip/hip_runtime.h>
#include <hip/hip_bf16.h>

#define N_NODES 50000
#define E_EDGES 300000
#define NGRAPH 64
#define NCHUNK 129
#define CSPLIT 65    // half 0: c in [0,65), half 1: c in [65,129)
#define NSTEPP 518   // NCHUNK*4 + 2 pad steps (prefetch distance 2 overrun)
#define NEGRP 1172   // ceil(E/256)
#define LNEPS 1e-5f
#define NBLK_N 196   // ceil(50000/256)
#define NBLK_P 12500 // N_NODES/4
// prescale so RTZ pack to f16 ~= round-to-nearest (adds ~0.5 ulp before trunc)
#define RPRE16 1.00048828125f

typedef _Float16 f16x8 __attribute__((ext_vector_type(8)));
typedef _Float16 f16x2 __attribute__((ext_vector_type(2)));
typedef float floatx4 __attribute__((ext_vector_type(4)));
typedef float f32x2 __attribute__((ext_vector_type(2)));
typedef unsigned int u32x4 __attribute__((ext_vector_type(4)));

// ---------------- prep: Tt2[step][h][kw] f16, step=kf>>5, kw=kf&31 ----------------
__global__ void k_prep(const float* __restrict__ w2, const float* __restrict__ b2,
                       _Float16* __restrict__ Tt2) {
  int idx = blockIdx.x * 256 + threadIdx.x;   // 4144 blocks cover NSTEPP*2048
  int step = idx >> 11;
  int rem = idx & 2047;
  int h = rem >> 5;
  int kw = rem & 31;
  int kf = step * 32 + kw;
  float v = 0.f;
  if (kf < 16384) {
    int k = kf >> 4, f = kf & 15;
    v = w2[k * 1024 + f * 64 + h];
  } else if (kf < 16400) {
    v = b2[(kf - 16384) * 64 + h];
  }
  Tt2[idx] = (_Float16)v;
}

__global__ void k_prepw(const float* __restrict__ w1, float* __restrict__ W1t) {
  int i = blockIdx.x * 256 + threadIdx.x;
  if (i < 8192) { int k = i >> 3, j = i & 7; W1t[i] = w1[j * 1024 + k]; }
}

// ---------------- CSR build ----------------
__global__ void k_cnt(const int* __restrict__ ei, int* __restrict__ degI) {
  int e = blockIdx.x * 256 + threadIdx.x;
  if (e < E_EDGES) atomicAdd(&degI[ei[E_EDGES + e]], 1);
}

__global__ void k_scanA(const int* __restrict__ degI, int* __restrict__ bsum) {
  __shared__ int sm[256];
  int t = threadIdx.x;
  int i = blockIdx.x * 256 + t;
  sm[t] = (i < N_NODES) ? degI[i] : 0;
  __syncthreads();
  for (int off = 128; off > 0; off >>= 1) {
    if (t < off) sm[t] += sm[t + off];
    __syncthreads();
  }
  if (t == 0) bsum[blockIdx.x] = sm[0];
}

__global__ void k_scanB(const int* __restrict__ bsum, int* __restrict__ bpre) {
  __shared__ int s[256];
  int t = threadIdx.x;
  int v = (t < NBLK_N) ? bsum[t] : 0;
  s[t] = v;
  __syncthreads();
  for (int off = 1; off < 256; off <<= 1) {
    int add = (t >= off) ? s[t - off] : 0;
    __syncthreads();
    s[t] += add;
    __syncthreads();
  }
  if (t < NBLK_N) bpre[t] = s[t] - v;
}

__global__ void k_scanC(const int* __restrict__ degI, const int* __restrict__ bpre,
                        int* __restrict__ rowptr, int* __restrict__ cursor) {
  __shared__ int s[256];
  int t = threadIdx.x;
  int i = blockIdx.x * 256 + t;
  int d = (i < N_NODES) ? degI[i] : 0;
  s[t] = d;
  __syncthreads();
  for (int off = 1; off < 256; off <<= 1) {
    int add = (t >= off) ? s[t - off] : 0;
    __syncthreads();
    s[t] += add;
    __syncthreads();
  }
  int r = bpre[blockIdx.x] + s[t] - d;   // exclusive
  if (i < N_NODES) {
    rowptr[i] = r;
    cursor[i] = r;
    if (i == N_NODES - 1) rowptr[N_NODES] = r + d;
  }
}

__global__ void k_scatter(const int* __restrict__ ei, int* __restrict__ cursor,
                          int* __restrict__ colsrc) {
  int e = blockIdx.x * 256 + threadIdx.x;
  if (e < E_EDGES) {
    int s = ei[e], d = ei[E_EDGES + e];
    int pos = atomicAdd(&cursor[d], 1);
    colsrc[pos] = s;
  }
}

// ---------------- NNConv fused MFMA GEMM, split-K x2, register-direct B (f16) ----------------
// R8: f16 MFMA path (A-build = 1 perm + 4 v_pk_mul_f16); 4-slot rotating B regs,
// prefetch distance 2 steps (~550 cyc cover at 3 waves/SIMD >> L2 latency).
// ZERO LDS, ZERO barriers. min-waves 3 (R3: (256,4) spills acc).
__global__ __launch_bounds__(256, 3)
void k_nnconv(const float* __restrict__ x, const int* __restrict__ ei,
              const float* __restrict__ ea, const float* __restrict__ W1t,
              const float* __restrict__ b1, const _Float16* __restrict__ Tt2,
              float* __restrict__ agg) {
  const int tid = threadIdx.x;
  const int lane = tid & 63;
  const int l15 = lane & 15;
  const int quad = lane >> 4;
  const bool qhi = (lane & 32) != 0;     // k_local = quad>>1: selects which r of the pair
  // splat selector: replicate chosen 16-bit half of ubuf into both halves
  const unsigned rsel = qhi ? 0x07060706u : 0x05040504u;
  const int grp = blockIdx.x >> 1;
  const int half = blockIdx.x & 1;
  const int cstart = half ? CSPLIT : 0;
  const int cend = half ? NCHUNK : CSPLIT;

  int e = grp * 256 + tid;
  bool valid = e < E_EDGES;
  int srcv = valid ? ei[e] : 0;
  int dstv = valid ? ei[E_EDGES + e] : -1;

  f32x2 ea2[4];
  {
    const float4* p = (const float4*)(ea + (size_t)(valid ? e : 0) * 8);
    float4 a0 = p[0], a1 = p[1];
    ea2[0] = (f32x2){a0.x, a0.y};
    ea2[1] = (f32x2){a0.z, a0.w};
    ea2[2] = (f32x2){a1.x, a1.y};
    ea2[3] = (f32x2){a1.z, a1.w};
  }

  // persistent x fragments packed to f16 pairs (4 regs per mb)
  const int f0 = (quad & 1) * 8;
  unsigned xh16[4][4];
#pragma unroll
  for (int mb = 0; mb < 4; ++mb) {
    int s = __shfl(srcv, mb * 16 + l15);
    const float4* px = (const float4*)(x + (size_t)s * 16 + f0);
    float4 v0 = px[0], v1 = px[1];
    xh16[mb][0] = __builtin_bit_cast(unsigned, __builtin_amdgcn_cvt_pkrtz(v0.x * RPRE16, v0.y * RPRE16));
    xh16[mb][1] = __builtin_bit_cast(unsigned, __builtin_amdgcn_cvt_pkrtz(v0.z * RPRE16, v0.w * RPRE16));
    xh16[mb][2] = __builtin_bit_cast(unsigned, __builtin_amdgcn_cvt_pkrtz(v1.x * RPRE16, v1.y * RPRE16));
    xh16[mb][3] = __builtin_bit_cast(unsigned, __builtin_amdgcn_cvt_pkrtz(v1.z * RPRE16, v1.w * RPRE16));
  }

  // bpermute byte addresses for r broadcast (lane mb*16+l15)
  int bpaddr[4];
#pragma unroll
  for (int mb = 0; mb < 4; ++mb) bpaddr[mb] = (mb * 16 + l15) * 4;

  // B stream pointer: per-lane offset inside a [64h][32kw] step-tile
  const _Float16* bp = Tt2 + (size_t)(cstart * 4) * 2048 + (l15 * 32 + quad * 8);

  f16x8 Bq[4][4];
  auto loadB = [&](int which) {
    Bq[which][0] = *(const f16x8*)(bp);
    Bq[which][1] = *(const f16x8*)(bp + 512);
    Bq[which][2] = *(const f16x8*)(bp + 1024);
    Bq[which][3] = *(const f16x8*)(bp + 1536);
    bp += 2048;
  };

  unsigned prr[4];   // f16-packed r pair per k-step: lo16=r[2ks], hi16=r[2ks+1]
  auto calcR = [&](int c, const float* w1p, const float* b1p) {
    if (c < 128) {   // uniform branch
#pragma unroll
      for (int ks = 0; ks < 4; ++ks) {
        float rv[2];
#pragma unroll
        for (int kk = 0; kk < 2; ++kk) {
          const f32x2* w = (const f32x2*)(w1p + (ks * 2 + kk) * 8);  // uniform -> s_load
          f32x2 s01 = ea2[0] * w[0] + ea2[1] * w[1];
          f32x2 s23 = ea2[2] * w[2] + ea2[3] * w[3];
          f32x2 s = s01 + s23;
          rv[kk] = fmaxf(b1p[ks * 2 + kk] + s[0] + s[1], 0.f) * RPRE16;
        }
        prr[ks] = __builtin_bit_cast(unsigned, __builtin_amdgcn_cvt_pkrtz(rv[0], rv[1]));
      }
    } else {
      prr[0] = 0x00003C00u;  // lo16 = f16(1.0) at k=1024 (b2 rows); rest 0
      prr[1] = prr[2] = prr[3] = 0u;
    }
  };

  unsigned ubuf[16]; // bpermuted r pairs for the CURRENT chunk, [ks*4+mb]
  auto bcastR = [&]() {
#pragma unroll
    for (int ks = 0; ks < 4; ++ks)
#pragma unroll
      for (int mb = 0; mb < 4; ++mb)
        ubuf[ks * 4 + mb] = (unsigned)__builtin_amdgcn_ds_bpermute(bpaddr[mb], (int)prr[ks]);
  };

  floatx4 acc[4][4];
#pragma unroll
  for (int mb = 0; mb < 4; ++mb)
#pragma unroll
    for (int nb = 0; nb < 4; ++nb) acc[mb][nb] = floatx4{0.f, 0.f, 0.f, 0.f};

  calcR(cstart, W1t + cstart * 64, b1 + cstart * 8);
  bcastR();
  loadB(0);
  loadB(1);
  const float* w1p = W1t + (cstart + 1) * 64;
  const float* b1p = b1 + (cstart + 1) * 8;

  for (int c = cstart; c < cend; ++c) {
#pragma unroll
    for (int ks = 0; ks < 4; ++ks) {
      loadB((ks + 2) & 3);   // prefetch 2 steps ahead (tail reads zero-pad steps)
#pragma unroll
      for (int mb = 0; mb < 4; ++mb) {
        f16x2 r2 = __builtin_bit_cast(f16x2,
            __builtin_amdgcn_perm(ubuf[ks * 4 + mb], 0u, rsel));
        u32x4 U;
#pragma unroll
        for (int j = 0; j < 4; ++j)
          U[j] = __builtin_bit_cast(unsigned,
                   __builtin_bit_cast(f16x2, xh16[mb][j]) * r2);
        f16x8 A = __builtin_bit_cast(f16x8, U);
#pragma unroll
        for (int nb = 0; nb < 4; ++nb)
          acc[mb][nb] = __builtin_amdgcn_mfma_f32_16x16x32_f16(A, Bq[ks][nb], acc[mb][nb], 0, 0, 0);
      }
    }
    if (c + 1 < cend) {
      calcR(c + 1, w1p, b1p);   // wave-synchronous; bpermutes wave-local
      bcastR();
      w1p += 64; b1p += 8;
    }
  }

  // epilogue: scatter partial msg to agg[dst]  (C layout: row=quad*4+reg, col=l15)
#pragma unroll
  for (int mb = 0; mb < 4; ++mb) {
#pragma unroll
    for (int reg = 0; reg < 4; ++reg) {
      int dd = __shfl(dstv, mb * 16 + quad * 4 + reg);
      if (dd >= 0) {
#pragma unroll
        for (int nb = 0; nb < 4; ++nb)
          atomicAdd(&agg[(size_t)dd * 64 + nb * 16 + l15], acc[mb][nb][reg]);
      }
    }
  }
}

// ---------------- h = relu(x@rootw + agg/deg + b); LN1 partials ----------------
__global__ void k_root(const float* __restrict__ x, const float* __restrict__ rootw,
                       const float* __restrict__ conv1b, const float* __restrict__ agg,
                       const int* __restrict__ degI, float* __restrict__ hpre,
                       float* __restrict__ rpart) {
  __shared__ float sW[1024];
  __shared__ float sx[64];
  __shared__ float red[8];
  int t = threadIdx.x;
  int blk = blockIdx.x;
#pragma unroll
  for (int i = 0; i < 4; ++i) sW[t + i * 256] = rootw[t + i * 256];
  if (t < 64) sx[t] = x[(size_t)blk * 64 + t];
  __syncthreads();
  int ln = t >> 6, h = t & 63;
  int n = blk * 4 + ln;
  float acc = conv1b[h];
#pragma unroll
  for (int f = 0; f < 16; ++f) acc += sx[ln * 16 + f] * sW[f * 64 + h];
  float dv = fmaxf((float)degI[n], 1.0f);
  float v = acc + agg[(size_t)n * 64 + h] / dv;
  v = fmaxf(v, 0.f);
  hpre[(size_t)n * 64 + h] = v;
  float s1 = v, s2 = v * v;
  for (int o = 32; o > 0; o >>= 1) { s1 += __shfl_down(s1, o); s2 += __shfl_down(s2, o); }
  if ((t & 63) == 0) { red[t >> 6] = s1; red[4 + (t >> 6)] = s2; }
  __syncthreads();
  if (t == 0) {
    rpart[blk * 2] = red[0] + red[1] + red[2] + red[3];
    rpart[blk * 2 + 1] = red[4] + red[5] + red[6] + red[7];
  }
}

// reduce LN1 partials; fold LN1 into gat_w
__global__ void k_fold1(const float* __restrict__ rpart, const float* __restrict__ n1w,
                        const float* __restrict__ n1b, const float* __restrict__ gatw,
                        float* __restrict__ gw2, float* __restrict__ tb) {
  __shared__ float red[8];
  __shared__ float sMI[2];
  __shared__ float sS[64], sT[64];
  int t = threadIdx.x;
  int wv = t >> 6, lane = t & 63;
  float a = 0.f, b = 0.f;
  for (int i = t; i < NBLK_P; i += 256) { a += rpart[2 * i]; b += rpart[2 * i + 1]; }
  for (int o = 32; o > 0; o >>= 1) { a += __shfl_down(a, o); b += __shfl_down(b, o); }
  if (lane == 0) { red[wv] = a; red[4 + wv] = b; }
  __syncthreads();
  if (t == 0) {
    float A = red[0] + red[1] + red[2] + red[3];
    float B = red[4] + red[5] + red[6] + red[7];
    const float M = (float)N_NODES * 64.f;
    float mu = A / M;
    float var = fmaxf(B / M - mu * mu, 0.f);
    sMI[0] = mu;
    sMI[1] = 1.f / (sqrtf(var) + LNEPS);
  }
  __syncthreads();
  if (t < 64) {
    float mu = sMI[0], inv = sMI[1];
    sS[t] = inv * n1w[t];
    sT[t] = n1b[t] - mu * inv * n1w[t];
  }
  __syncthreads();
  if (t < 64) {
    float acc = 0.f;
    for (int i = 0; i < 64; ++i) {
      float g = gatw[i * 64 + t];
      gw2[i * 64 + t] = sS[i] * g;
      acc += sT[i] * g;
    }
    tb[t] = acc;
  }
}

// xh = hpre@gw2 + tb ; attention scalars
__global__ void k_gatlin(const float* __restrict__ hpre, const float* __restrict__ gw2,
                         const float* __restrict__ tb, const float* __restrict__ attS,
                         const float* __restrict__ attD, float* __restrict__ xh,
                         float* __restrict__ asrc, float* __restrict__ adst) {
  __shared__ float sW[4096];
  __shared__ float sh[256];
  __shared__ float sxh[256];
  int t = threadIdx.x;
  int blk = blockIdx.x;
#pragma unroll
  for (int i = 0; i < 16; ++i) sW[t + i * 256] = gw2[t + i * 256];
  sh[t] = hpre[(size_t)blk * 256 + t];
  __syncthreads();
  int ln = t >> 6, h = t & 63;
  float acc = tb[h];
  for (int i = 0; i < 64; ++i) acc += sh[ln * 64 + i] * sW[i * 64 + h];
  xh[(size_t)blk * 256 + t] = acc;
  sxh[t] = acc;
  __syncthreads();
  if (t < 32) {
    int ln2 = t >> 3, rem = t & 7;
    int hd = rem & 3;
    const float* av = (rem >> 2) ? attD : attS;
    float a = 0.f;
#pragma unroll
    for (int d = 0; d < 16; ++d) a += sxh[ln2 * 64 + hd * 16 + d] * av[hd * 16 + d];
    int n = blk * 4 + ln2;
    if (rem >> 2) adst[n * 4 + hd] = a; else asrc[n * 4 + hd] = a;
  }
}

// ---------------- GAT: CSR gather, online softmax, fused relu + LN2 partials ----------------
__global__ void k_gat(const int* __restrict__ rowptr, const int* __restrict__ colsrc,
                      const float* __restrict__ xh, const float* __restrict__ asrc,
                      const float* __restrict__ adst, const float* __restrict__ gatb,
                      float* __restrict__ act, float* __restrict__ gpart) {
  __shared__ float sP[4][256];
  __shared__ int sS[4][64];
  __shared__ float sRed[8];
  int t = threadIdx.x;
  int wv = t >> 6, lane = t & 63;
  int n = blockIdx.x * 4 + wv;
  int start = rowptr[n], end = rowptr[n + 1];
  int deg = end - start;
  int myhd = lane >> 4;
  float ad[4];
#pragma unroll
  for (int hd = 0; hd < 4; ++hd) ad[hd] = adst[n * 4 + hd];
  float m[4] = {-1e30f, -1e30f, -1e30f, -1e30f};
  float l[4] = {0.f, 0.f, 0.f, 0.f};
  float O = 0.f;
  int items = deg + 1;  // + self loop
  for (int t0 = 0; t0 < items; t0 += 64) {
    int cnt = min(64, items - t0);
    int idx = t0 + lane;
    bool has = lane < cnt;
    int s = n;
    if (has && idx < deg) s = colsrc[start + idx];
    float a[4];
#pragma unroll
    for (int hd = 0; hd < 4; ++hd) {
      float av = has ? (asrc[s * 4 + hd] + ad[hd]) : -1e30f;
      a[hd] = (av > 0.f) ? av : 0.2f * av;  // leaky relu 0.2
    }
    float tm[4];
#pragma unroll
    for (int hd = 0; hd < 4; ++hd) tm[hd] = a[hd];
#pragma unroll
    for (int off = 32; off > 0; off >>= 1)
#pragma unroll
      for (int hd = 0; hd < 4; ++hd) tm[hd] = fmaxf(tm[hd], __shfl_xor(tm[hd], off));
    float p[4];
#pragma unroll
    for (int hd = 0; hd < 4; ++hd) {
      float mn = fmaxf(m[hd], tm[hd]);
      float sc = __expf(m[hd] - mn);
      l[hd] *= sc;
      if (hd == myhd) O *= sc;
      m[hd] = mn;
      p[hd] = has ? __expf(a[hd] - mn) : 0.f;
    }
    float ts[4];
#pragma unroll
    for (int hd = 0; hd < 4; ++hd) ts[hd] = p[hd];
#pragma unroll
    for (int off = 32; off > 0; off >>= 1)
#pragma unroll
      for (int hd = 0; hd < 4; ++hd) ts[hd] += __shfl_xor(ts[hd], off);
#pragma unroll
    for (int hd = 0; hd < 4; ++hd) l[hd] += ts[hd];
    sS[wv][lane] = s;
#pragma unroll
    for (int hd = 0; hd < 4; ++hd) sP[wv][lane * 4 + hd] = p[hd];
    // wave-private LDS region: program order suffices, no barrier
    for (int e2 = 0; e2 < cnt; ++e2) {
      int ss = sS[wv][e2];
      float pp = sP[wv][e2 * 4 + myhd];
      O = fmaf(pp, xh[(size_t)ss * 64 + lane], O);
    }
  }
  float lmy = (myhd & 2) ? ((myhd & 1) ? l[3] : l[2]) : ((myhd & 1) ? l[1] : l[0]);
  float outv = O / (lmy + 1e-16f);
  float v = fmaxf(outv + gatb[lane], 0.f);
  act[(size_t)n * 64 + lane] = v;
  float s1 = v, s2 = v * v;
#pragma unroll
  for (int off = 32; off > 0; off >>= 1) { s1 += __shfl_down(s1, off); s2 += __shfl_down(s2, off); }
  if (lane == 0) { sRed[wv] = s1; sRed[4 + wv] = s2; }
  __syncthreads();
  if (t == 0) {
    gpart[blockIdx.x * 2] = sRed[0] + sRed[1] + sRed[2] + sRed[3];
    gpart[blockIdx.x * 2 + 1] = sRed[4] + sRed[5] + sRed[6] + sRed[7];
  }
}

// reduce LN2 partials; fold LN2 + linear head into wl
__global__ void k_fold2(const float* __restrict__ gpart, const float* __restrict__ n2w,
                        const float* __restrict__ n2b, const float* __restrict__ linw,
                        const float* __restrict__ linb, float* __restrict__ wl) {
  __shared__ float red[8];
  __shared__ float sMI[2];
  int t = threadIdx.x;
  int wv = t >> 6, lane = t & 63;
  float a = 0.f, b = 0.f;
  for (int i = t; i < NBLK_P; i += 256) { a += gpart[2 * i]; b += gpart[2 * i + 1]; }
  for (int o = 32; o > 0; o >>= 1) { a += __shfl_down(a, o); b += __shfl_down(b, o); }
  if (lane == 0) { red[wv] = a; red[4 + wv] = b; }
  __syncthreads();
  if (t == 0) {
    float A = red[0] + red[1] + red[2] + red[3];
    float B = red[4] + red[5] + red[6] + red[7];
    const float M = (float)N_NODES * 64.f;
    float mu = A / M;
    float var = fmaxf(B / M - mu * mu, 0.f);
    sMI[0] = mu;
    sMI[1] = 1.f / (sqrtf(var) + LNEPS);
  }
  __syncthreads();
  if (t < 64) {
    float mu = sMI[0], inv = sMI[1];
    float w = inv * n2w[t] * linw[t];
    float p = (n2b[t] - mu * inv * n2w[t]) * linw[t];
    wl[t] = w;
    for (int o = 32; o > 0; o >>= 1) p += __shfl_down(p, o);
    if (t == 0) wl[64] = p + linb[0];
  }
}

// per-graph segmented pool + head (batch is sorted; zero atomics)
__global__ void k_out(const float* __restrict__ act, const float* __restrict__ wl,
                      const int* __restrict__ batch, float* __restrict__ out) {
  __shared__ float red[4];
  __shared__ float swl[64];
  int g = blockIdx.x;
  int t = threadIdx.x;
  int wv = t >> 6, lane = t & 63;
  if (t < 64) swl[t] = wl[t];
  __syncthreads();
  auto lbound = [&](int key) {
    int lo = 0, hi = N_NODES;
    while (lo < hi) { int mid = (lo + hi) >> 1; if (batch[mid] < key) lo = mid + 1; else hi = mid; }
    return lo;
  };
  int lo = lbound(g), hi = lbound(g + 1);
  int cntn = hi - lo;
  float s = 0.f;
  for (int idx = t; idx < cntn * 64; idx += 256) {
    int n = lo + (idx >> 6);
    int d = idx & 63;
    s += act[(size_t)n * 64 + d] * swl[d];
  }
  for (int o = 32; o > 0; o >>= 1) s += __shfl_down(s, o);
  if (lane == 0) red[wv] = s;
  __syncthreads();
  if (t == 0)
    out[g] = (red[0] + red[1] + red[2] + red[3]) / fmaxf((float)cntn, 1.f) + wl[64];
}

// ---------------- workspace layout (bytes, 64B aligned) ----------------
#define OFF_AGG     0UL
#define OFF_DEGI    12800000UL
#define ZBYTES      13000000UL
#define OFF_RPART   13000000UL
#define OFF_GPART   13100032UL
#define OFF_ROWPTR  13200064UL
#define OFF_CURSOR  13400128UL
#define OFF_BSUM    13600192UL
#define OFF_BPRE    13601024UL
#define OFF_COLSRC  13601856UL
#define OFF_TT      14801856UL   // NSTEPP*2048*2 = 2121728 (incl. 2 zero pad steps)
#define OFF_W1T     16923584UL
#define OFF_GW2     16956352UL
#define OFF_TB      16972736UL
#define OFF_WL      16972992UL
#define OFF_ASRC    16973312UL
#define OFF_ADST    17773312UL
#define OFF_HPRE    18573312UL
#define OFF_XH      31373312UL
#define OFF_ACT     44173312UL
#define WS_NEED     56973312UL

extern "C" void kernel_launch(void* const* d_in, const int* in_sizes, int n_in,
                              void* d_out, int out_size, void* d_ws, size_t ws_size,
                              hipStream_t stream) {
  const float* x = (const float*)d_in[0];
  const int* ei = (const int*)d_in[1];
  const float* ea = (const float*)d_in[2];
  const int* batch = (const int*)d_in[3];
  const float* w1 = (const float*)d_in[4];
  const float* b1 = (const float*)d_in[5];
  const float* w2 = (const float*)d_in[6];
  const float* b2 = (const float*)d_in[7];
  const float* rootw = (const float*)d_in[8];
  const float* conv1b = (const float*)d_in[9];
  const float* n1w = (const float*)d_in[10];
  const float* n1b = (const float*)d_in[11];
  const float* gatw = (const float*)d_in[12];
  const float* attS = (const float*)d_in[13];
  const float* attD = (const float*)d_in[14];
  const float* gatb = (const float*)d_in[15];
  const float* n2w = (const float*)d_in[16];
  const float* n2b = (const float*)d_in[17];
  const float* linw = (const float*)d_in[18];
  const float* linb = (const float*)d_in[19];

  if (ws_size < WS_NEED) return;
  char* ws = (char*)d_ws;
  float* agg    = (float*)(ws + OFF_AGG);
  int* degI     = (int*)(ws + OFF_DEGI);
  float* rpart  = (float*)(ws + OFF_RPART);
  float* gpart  = (float*)(ws + OFF_GPART);
  int* rowptr   = (int*)(ws + OFF_ROWPTR);
  int* cursor   = (int*)(ws + OFF_CURSOR);
  int* bsum     = (int*)(ws + OFF_BSUM);
  int* bpre     = (int*)(ws + OFF_BPRE);
  int* colsrc   = (int*)(ws + OFF_COLSRC);
  _Float16* Tt2 = (_Float16*)(ws + OFF_TT);
  float* W1t    = (float*)(ws + OFF_W1T);
  float* gw2    = (float*)(ws + OFF_GW2);
  float* tb     = (float*)(ws + OFF_TB);
  float* wl     = (float*)(ws + OFF_WL);
  float* asrc   = (float*)(ws + OFF_ASRC);
  float* adst   = (float*)(ws + OFF_ADST);
  float* hpre   = (float*)(ws + OFF_HPRE);
  float* xh     = (float*)(ws + OFF_XH);
  float* act    = (float*)(ws + OFF_ACT);

  hipMemsetAsync(ws, 0, ZBYTES, stream);

  k_prep<<<NSTEPP * 8, 256, 0, stream>>>(w2, b2, Tt2);   // 518*2048/256
  k_prepw<<<32, 256, 0, stream>>>(w1, W1t);
  k_cnt<<<(E_EDGES + 255) / 256, 256, 0, stream>>>(ei, degI);
  k_scanA<<<NBLK_N, 256, 0, stream>>>(degI, bsum);
  k_scanB<<<1, 256, 0, stream>>>(bsum, bpre);
  k_scanC<<<NBLK_N, 256, 0, stream>>>(degI, bpre, rowptr, cursor);
  k_scatter<<<(E_EDGES + 255) / 256, 256, 0, stream>>>(ei, cursor, colsrc);
  k_nnconv<<<NEGRP * 2, 256, 0, stream>>>(x, ei, ea, W1t, b1, Tt2, agg);
  k_root<<<NBLK_P, 256, 0, stream>>>(x, rootw, conv1b, agg, degI, hpre, rpart);
  k_fold1<<<1, 256, 0, stream>>>(rpart, n1w, n1b, gatw, gw2, tb);
  k_gatlin<<<NBLK_P, 256, 0, stream>>>(hpre, gw2, tb, attS, attD, xh, asrc, adst);
  k_gat<<<NBLK_P, 256, 0, stream>>>(rowptr, colsrc, xh, asrc, adst, gatb, act, gpart);
  k_fold2<<<1, 256, 0, stream>>>(gpart, n2w, n2b, linw, linb, wl);
  k_out<<<NGRAPH, 256, 0, stream>>>(act, wl, batch, (float*)d_out);
}